// Round 2
// baseline (3754.136 us; speedup 1.0000x reference)
//
#include <hip/hip_runtime.h>
#include <math.h>

#define BB 2
#define C0 96
#define LTOT 13824
#define DINC 192
#define L4S 3456
#define NCHUNK 108
#define CLEN 128

// Static device workspace (avoids d_ws size limits; ~316 MB .bss)
#define WS_FLOATS 78879744
__device__ float g_ws[WS_FLOATS];

__device__ __forceinline__ int sigma_idx(int dir, int p){
  if (dir == 0) return p;
  if (dir == 1) return LTOT - 1 - p;
  return 4*(p % L4S) + (p / L4S);   // slice_perm: out[s*L4+j] = in[4j+s]
}

__device__ __forceinline__ float silu_f(float x){
  return x / (1.f + __expf(-x));
}

// ---------------- LayerNorm: x (B,96,L) -> xnorm (B,L,96) ----------------
__global__ __launch_bounds__(256) void k_ln(const float* __restrict__ x,
    const float* __restrict__ g, const float* __restrict__ bt, float* __restrict__ xn)
{
  int i = blockIdx.x*256 + threadIdx.x;           // over B*L
  if (i >= BB*LTOT) return;
  int b = i / LTOT, ll = i % LTOT;
  const float* xp = x + (size_t)b*C0*LTOT + ll;
  float s = 0.f, ss = 0.f;
  for (int c = 0; c < C0; ++c){ float v = xp[(size_t)c*LTOT]; s += v; ss += v*v; }
  float mu = s * (1.f/C0);
  float var = ss * (1.f/C0) - mu*mu;
  float inv = rsqrtf(var + 1e-5f);
  float* op = xn + (size_t)i*C0;
  for (int c = 0; c < C0; ++c){
    float v = xp[(size_t)c*LTOT];
    op[c] = (v - mu)*inv*g[c] + bt[c];
  }
}

// ---------------- Generic tiled GEMM: O = A(MxK) * W(NxK)^T ----------------
// modes: 0 = in_proj split (O0=xin col<192, O1=silu gate col>=192)
//        1 = plain store O0[row*ldo+col]
//        2 = softplus(acc + bias[wb*bias_stride+col]) -> O0
//        3 = transposed store O0[(b*N+col)*rpb + l], b=row/rpb
__global__ __launch_bounds__(256) void k_gemm(
    const float* __restrict__ A, const float* __restrict__ A2, const float* __restrict__ A3,
    int lda, const float* __restrict__ W, long wstride, const float* __restrict__ bias,
    int bias_stride, int N, int K, int rpb,
    float* __restrict__ O0, float* __restrict__ O1, int ldo, int mode)
{
  __shared__ float As[32][65];
  __shared__ float Ws[32][65];
  int tid = threadIdx.x;
  long row0 = (long)blockIdx.x * 64;
  int col0 = blockIdx.y * 64;
  int wb = (int)(row0 / rpb);
  const float* Wp = W + (long)wb * wstride;
  float acc[4][4] = {};
  int kk = tid & 31, rb = tid >> 5;
  int nk = (K + 31) >> 5;
  for (int kc = 0; kc < nk; ++kc){
    int k0 = kc*32;
    bool kin = (k0 + kk) < K;
    #pragma unroll
    for (int rr = 0; rr < 8; ++rr){
      int r = rb + rr*8;
      float a = 0.f;
      if (kin){
        long idx = (row0 + r)*(long)lda + k0 + kk;
        a = A[idx];
        if (A2) a += A2[idx] + A3[idx];
      }
      As[kk][r] = a;
      float wv = 0.f;
      if ((col0 + r) < N && kin) wv = Wp[(long)(col0 + r)*K + k0 + kk];
      Ws[kk][r] = wv;
    }
    __syncthreads();
    int r0 = (tid & 15)*4, c0 = (tid >> 4)*4;
    #pragma unroll
    for (int k = 0; k < 32; ++k){
      float av[4], wv[4];
      #pragma unroll
      for (int i = 0; i < 4; ++i){ av[i] = As[k][r0+i]; wv[i] = Ws[k][c0+i]; }
      #pragma unroll
      for (int i = 0; i < 4; ++i)
        #pragma unroll
        for (int j = 0; j < 4; ++j) acc[i][j] += av[i]*wv[j];
    }
    __syncthreads();
  }
  int r0 = (tid & 15)*4, c0 = (tid >> 4)*4;
  #pragma unroll
  for (int i = 0; i < 4; ++i){
    long row = row0 + r0 + i;
    #pragma unroll
    for (int j = 0; j < 4; ++j){
      int col = col0 + c0 + j;
      if (col >= N) continue;
      float v = acc[i][j];
      if (mode == 0){
        if (col < DINC) O0[row*DINC + col] = v;
        else            O1[row*DINC + col - DINC] = silu_f(v);
      } else if (mode == 1){
        O0[row*(long)ldo + col] = v;
      } else if (mode == 2){
        float xv = v + bias[wb*bias_stride + col];
        O0[row*(long)ldo + col] = (xv > 20.f) ? xv : log1pf(__expf(xv));
      } else {
        long b = row / rpb, l = row % rpb;
        O0[((long)b*N + col)*rpb + l] = v;
      }
    }
  }
}

// ---------------- depthwise causal conv1d (permuted) + SiLU ----------------
__global__ __launch_bounds__(256) void k_dwconv(const float* __restrict__ xin,
    const float* __restrict__ cw, const float* __restrict__ cb, float* __restrict__ u)
{
  long i = (long)blockIdx.x*256 + threadIdx.x;   // over 3*B*L*192
  if (i >= 3L*BB*LTOT*DINC) return;
  int d = (int)(i % DINC); long t = i / DINC;
  int p = (int)(t % LTOT); t /= LTOT;
  int b = (int)(t % BB); int dir = (int)(t / BB);
  float acc = cb[dir*DINC + d];
  const float* wp = cw + ((long)dir*DINC + d)*4;
  #pragma unroll
  for (int kk = 0; kk < 4; ++kk){
    int pp = p - 3 + kk;
    if (pp >= 0){
      int l = sigma_idx(dir, pp);
      acc += xin[((long)b*LTOT + l)*DINC + d] * wp[kk];
    }
  }
  u[i] = silu_f(acc);
}

// ---------------- A = -exp(A_log) ----------------
__global__ __launch_bounds__(256) void k_prepA(const float* __restrict__ al, float* __restrict__ A){
  int i = blockIdx.x*256 + threadIdx.x;
  if (i < 3*DINC*16) A[i] = -__expf(al[i]);
}

// ---------------- scan phase 1: per-chunk local scan ----------------
__global__ __launch_bounds__(256) void k_scan1(const float* __restrict__ u,
    const float* __restrict__ dt, const float* __restrict__ xdbl,
    const float* __restrict__ Abuf, float* __restrict__ aprod, float* __restrict__ hend)
{
  long i = (long)blockIdx.x*256 + threadIdx.x;   // ((bd*NC+c)*192+d)*16+s
  int s = (int)(i & 15); long t = i >> 4;
  int d = (int)(t % DINC); t /= DINC;
  int c = (int)(t % NCHUNK); int bd = (int)(t / NCHUNK);
  int dir = bd >> 1;
  float Av = Abuf[((long)dir*DINC + d)*16 + s];
  long pbase = (long)bd*LTOT + (long)c*CLEN;
  float h = 0.f, ap = 1.f;
  for (int j = 0; j < CLEN; ++j){
    long p = pbase + j;
    float ldt = dt[p*DINC + d];
    float lu  = u [p*DINC + d];
    float bb  = xdbl[p*38 + 6 + s];
    float dA = __expf(ldt * Av);
    h = dA*h + ldt*lu*bb;
    ap *= dA;
  }
  long oi = (((long)bd*DINC + d)*NCHUNK + c)*16 + s;
  aprod[oi] = ap; hend[oi] = h;
}

// ---------------- scan phase 2: scan over chunks; aprod becomes h_in ----------------
__global__ __launch_bounds__(256) void k_scan2(float* __restrict__ aprod, const float* __restrict__ hend){
  long i = (long)blockIdx.x*256 + threadIdx.x;   // (bd*192+d)*16+s
  if (i >= 6L*DINC*16) return;
  int s = (int)(i & 15); long t = i >> 4;
  int d = (int)(t % DINC); int bd = (int)(t / DINC);
  long base = (((long)bd*DINC + d)*NCHUNK)*16 + s;
  float H = 0.f;
  for (int c = 0; c < NCHUNK; ++c){
    long idx = base + (long)c*16;
    float a = aprod[idx], he = hend[idx];
    aprod[idx] = H;            // h_in for chunk c
    H = he + a*H;
  }
}

// ---------------- scan phase 3: recompute with true h_in, reduce over s, gate+inv-perm ----------------
__global__ __launch_bounds__(256) void k_scan3(const float* __restrict__ u,
    const float* __restrict__ dt, const float* __restrict__ xdbl,
    const float* __restrict__ Abuf, const float* __restrict__ hin,
    const float* __restrict__ Dp, const float* __restrict__ gate, float* __restrict__ qkv)
{
  int tid = threadIdx.x;
  int s = tid & 15, di = tid >> 4;
  int c  = blockIdx.x % NCHUNK;
  int dg = blockIdx.x / NCHUNK;
  int bd = blockIdx.y;
  int dir = bd >> 1, b = bd & 1;
  int d = dg*16 + di;
  float Av = Abuf[((long)dir*DINC + d)*16 + s];
  float Dv = Dp[dir*DINC + d];
  float h = hin[(((long)bd*DINC + d)*NCHUNK + c)*16 + s];
  long pbase = (long)bd*LTOT + (long)c*CLEN;
  for (int j = 0; j < CLEN; ++j){
    long p = pbase + j;
    float ldt = dt[p*DINC + d];
    float lu  = u [p*DINC + d];
    float bb  = xdbl[p*38 + 6  + s];
    float cc  = xdbl[p*38 + 22 + s];
    float dA = __expf(ldt * Av);
    h = dA*h + ldt*lu*bb;
    float yv = h*cc;
    yv += __shfl_xor(yv, 1);
    yv += __shfl_xor(yv, 2);
    yv += __shfl_xor(yv, 4);
    yv += __shfl_xor(yv, 8);
    if (s == 0){
      int pl = (int)(p - (long)bd*LTOT);
      int l = sigma_idx(dir, pl);
      long li = (long)b*LTOT + l;
      qkv[(((long)dir*BB + b)*LTOT + l)*DINC + d] = (yv + lu*Dv) * gate[li*DINC + d];
    }
  }
}

// ---------------- zero small buffer ----------------
__global__ __launch_bounds__(256) void k_zero(float* __restrict__ p, int n){
  int i = blockIdx.x*256 + threadIdx.x;
  if (i < n) p[i] = 0.f;
}

// ---------------- attn_raw[b,d,e] += sum_l q[b,l,d] k[b,l,e] (split-L atomics) ----------------
__global__ __launch_bounds__(256) void k_qk(const float* __restrict__ q,
    const float* __restrict__ k, float* __restrict__ attn)
{
  __shared__ float Qs[32][64];
  __shared__ float Ks[32][64];
  int tid = threadIdx.x;
  int bx = blockIdx.x;
  int lc = bx % 24; int et = (bx/24) % 3; int dtl = (bx/72) % 3; int b = bx/216;
  long base = (long)b*LTOT;
  int l0 = lc*576;
  float acc[4][4] = {};
  int col = tid & 63, rbase = tid >> 6;
  for (int ls = 0; ls < 576; ls += 32){
    #pragma unroll
    for (int rr = 0; rr < 8; ++rr){
      int r = rbase + rr*4;
      long l = base + l0 + ls + r;
      Qs[r][col] = q[l*DINC + dtl*64 + col];
      Ks[r][col] = k[l*DINC + et *64 + col];
    }
    __syncthreads();
    int d0 = (tid & 15)*4, e0 = (tid >> 4)*4;
    #pragma unroll
    for (int ll = 0; ll < 32; ++ll){
      float qa[4], ka[4];
      #pragma unroll
      for (int i = 0; i < 4; ++i){ qa[i] = Qs[ll][d0+i]; ka[i] = Ks[ll][e0+i]; }
      #pragma unroll
      for (int i = 0; i < 4; ++i)
        #pragma unroll
        for (int j = 0; j < 4; ++j) acc[i][j] += qa[i]*ka[j];
    }
    __syncthreads();
  }
  int d0 = (tid & 15)*4, e0 = (tid >> 4)*4;
  #pragma unroll
  for (int i = 0; i < 4; ++i)
    #pragma unroll
    for (int j = 0; j < 4; ++j)
      atomicAdd(&attn[((long)b*DINC + dtl*64 + d0 + i)*DINC + et*64 + e0 + j], acc[i][j]);
}

// ---------------- row softmax over e (192), one wave per row ----------------
__global__ __launch_bounds__(64) void k_softmax(float* __restrict__ attn){
  int row = blockIdx.x, tid = threadIdx.x;
  float* p = attn + (long)row*DINC;
  float v0 = p[tid], v1 = p[tid+64], v2 = p[tid+128];
  float m = fmaxf(v0, fmaxf(v1, v2));
  #pragma unroll
  for (int off = 32; off >= 1; off >>= 1) m = fmaxf(m, __shfl_xor(m, off));
  float e0 = __expf(v0-m), e1 = __expf(v1-m), e2 = __expf(v2-m);
  float s = e0 + e1 + e2;
  #pragma unroll
  for (int off = 32; off >= 1; off >>= 1) s += __shfl_xor(s, off);
  float inv = 1.f/s;
  p[tid] = e0*inv; p[tid+64] = e1*inv; p[tid+128] = e2*inv;
}

// ---------------- conv3d 3x3x3, pad 1: in 192ch -> out 96ch ----------------
// block = (b, h, ocg of 8); 576 threads over (w,z); per-ic 3x26x26 LDS slab
__global__ __launch_bounds__(576) void k_conv3(
    const float* __restrict__ in0, int c0, const float* __restrict__ in1,
    const float* __restrict__ wgt, const float* __restrict__ bias,
    const float* __restrict__ addx, float* __restrict__ out)
{
  __shared__ float slab[3*676];
  int tid = threadIdx.x;
  int bx = blockIdx.x;
  int g = bx % 12; int h = (bx/12) % 24; int b = bx / 288;
  int ww = tid / 24, zz = tid % 24;
  float acc[8] = {};
  const int SP = LTOT;
  for (int ic = 0; ic < 192; ++ic){
    const float* src = (ic < c0) ? (in0 + ((long)b*c0 + ic)*SP)
                                 : (in1 + ((long)b*(192-c0) + (ic-c0))*SP);
    for (int idx = tid; idx < 3*676; idx += 576){
      int pl = idx / 676, r = idx % 676;
      int wy = r / 26, zx = r % 26;
      int gh = h + pl - 1, gw = wy - 1, gz = zx - 1;
      float v = 0.f;
      if ((unsigned)gh < 24u && (unsigned)gw < 24u && (unsigned)gz < 24u)
        v = src[gh*576 + gw*24 + gz];
      slab[idx] = v;
    }
    __syncthreads();
    const float* wp = wgt + ((long)(g*8)*192 + ic)*27;
    #pragma unroll
    for (int kd = 0; kd < 3; ++kd)
      #pragma unroll
      for (int kw = 0; kw < 3; ++kw)
        #pragma unroll
        for (int kz = 0; kz < 3; ++kz){
          float v = slab[kd*676 + (ww+kw)*26 + (zz+kz)];
          int t27 = (kd*3 + kw)*3 + kz;
          #pragma unroll
          for (int oc = 0; oc < 8; ++oc) acc[oc] += v * wp[(long)oc*5184 + t27];
        }
    __syncthreads();
  }
  long osp = (long)h*576 + ww*24 + zz;
  #pragma unroll
  for (int oc = 0; oc < 8; ++oc){
    int oco = g*8 + oc;
    long oi = ((long)b*96 + oco)*SP + osp;
    float v = acc[oc] + bias[oco];
    if (addx) v += addx[oi];
    out[oi] = v;
  }
}

extern "C" void kernel_launch(void* const* d_in, const int* in_sizes, int n_in,
                              void* d_out, int out_size, void* d_ws, size_t ws_size,
                              hipStream_t stream)
{
  const float* x          = (const float*)d_in[0];
  const float* ln_g       = (const float*)d_in[1];
  const float* ln_b       = (const float*)d_in[2];
  const float* in_proj_w  = (const float*)d_in[3];
  const float* conv_w     = (const float*)d_in[4];
  const float* conv_b     = (const float*)d_in[5];
  const float* xproj_w    = (const float*)d_in[6];
  const float* dt_w       = (const float*)d_in[7];
  const float* dt_b       = (const float*)d_in[8];
  const float* A_log      = (const float*)d_in[9];
  const float* Dp         = (const float*)d_in[10];
  const float* out_proj_w = (const float*)d_in[11];
  const float* f1_w       = (const float*)d_in[12];
  const float* f1_b       = (const float*)d_in[13];
  const float* f2_w       = (const float*)d_in[14];
  const float* f2_b       = (const float*)d_in[15];
  float* out = (float*)d_out;

  const size_t BL = (size_t)BB*LTOT;     // 27648
  const size_t S  = BL*DINC;             // 5,308,416

  // static workspace (no reliance on ws_size)
  void* wsp = nullptr;
  (void)hipGetSymbolAddress(&wsp, HIP_SYMBOL(g_ws));
  float* ws = (float*)wsp;
  size_t off = 0;
  auto alloc = [&](size_t n){ float* p = ws + off; off += n; return p; };
  float* xnorm = alloc(BL*C0);
  float* xin   = alloc(S);
  float* gate  = alloc(S);
  float* u     = alloc(3*S);
  float* dtb   = alloc(3*S);
  float* xdbl  = alloc(3*BL*38);
  float* qkv   = alloc(3*S);
  float* Abuf  = alloc(3*DINC*16);
  float* aprod = alloc((size_t)6*DINC*16*NCHUNK);   // becomes h_in after scan2
  float* hend  = alloc((size_t)6*DINC*16*NCHUNK);
  float* attn  = alloc((size_t)BB*DINC*DINC);
  float* outa  = alloc(S);
  float* outm  = alloc(BL*C0);
  float* outc1 = alloc(BL*C0);

  // 1) layernorm + transpose
  k_ln<<<108, 256, 0, stream>>>(x, ln_g, ln_b, xnorm);
  // 2) in_proj -> xin + silu gate
  k_gemm<<<dim3(432, 6), 256, 0, stream>>>(xnorm, nullptr, nullptr, 96,
      in_proj_w, 0, nullptr, 0, 384, 96, (int)BL, xin, gate, DINC, 0);
  // 3) depthwise causal conv + silu (all 3 directions batched)
  k_dwconv<<<62208, 256, 0, stream>>>(xin, conv_w, conv_b, u);
  // 4) xproj: u -> xdbl (dtr|Bc|Cc)
  k_gemm<<<dim3(1296, 1), 256, 0, stream>>>(u, nullptr, nullptr, DINC,
      xproj_w, 38L*192, nullptr, 0, 38, 192, (int)BL, xdbl, nullptr, 38, 1);
  // 5) dt proj + softplus
  k_gemm<<<dim3(1296, 3), 256, 0, stream>>>(xdbl, nullptr, nullptr, 38,
      dt_w, 192L*6, dt_b, 192, 192, 6, (int)BL, dtb, nullptr, DINC, 2);
  // 6) A = -exp(A_log)
  k_prepA<<<36, 256, 0, stream>>>(A_log, Abuf);
  // 7) chunked selective scan
  k_scan1<<<7776, 256, 0, stream>>>(u, dtb, xdbl, Abuf, aprod, hend);
  k_scan2<<<72, 256, 0, stream>>>(aprod, hend);
  k_scan3<<<dim3(NCHUNK*12, 6), 256, 0, stream>>>(u, dtb, xdbl, Abuf, aprod, Dp, gate, qkv);
  // 8) attention matrix + softmax
  k_zero<<<288, 256, 0, stream>>>(attn, BB*DINC*DINC);
  k_qk<<<432, 256, 0, stream>>>(qkv, qkv + S, attn);
  k_softmax<<<BB*DINC, 64, 0, stream>>>(attn);
  // 9) out_a = v @ attn^T  (per-batch weights)
  k_gemm<<<dim3(432, 3), 256, 0, stream>>>(qkv + 2*S, nullptr, nullptr, DINC,
      attn, (long)DINC*DINC, nullptr, 0, DINC, DINC, LTOT, outa, nullptr, DINC, 1);
  // 10) out_m = (q+k+v) @ out_proj^T, stored (B,C,L)
  k_gemm<<<dim3(432, 2), 256, 0, stream>>>(qkv, qkv + S, qkv + 2*S, DINC,
      out_proj_w, 0, nullptr, 0, 96, 192, LTOT, outm, nullptr, 0, 3);
  // 11) conv3d #1: out_a (viewed (B,192,SP) row-major) -> outc1
  k_conv3<<<576, 576, 0, stream>>>(outa, 192, nullptr, f1_w, f1_b, nullptr, outc1);
  // 12) conv3d #2: concat(outc1, outm) -> out2 + x -> d_out
  k_conv3<<<576, 576, 0, stream>>>(outc1, 96, outm, f2_w, f2_b, x, out);
}

// Round 3
// 1392.887 us; speedup vs baseline: 2.6952x; 2.6952x over previous
//
#include <hip/hip_runtime.h>
#include <hip/hip_bf16.h>
#include <math.h>

#define BB 2
#define C0 96
#define LTOT 13824
#define DINC 192
#define L4S 3456
#define NCHUNK 108
#define CLEN 128

// Static device workspace
#define WS_FLOATS 87500000
__device__ __attribute__((aligned(256))) float g_ws[WS_FLOATS];

typedef __bf16 bf16x8 __attribute__((ext_vector_type(8)));
typedef short  s16x8  __attribute__((ext_vector_type(8)));
typedef float  f32x4  __attribute__((ext_vector_type(4)));

__device__ __forceinline__ f32x4 mfma16(s16x8 a, s16x8 b, f32x4 c){
  return __builtin_amdgcn_mfma_f32_16x16x32_bf16(
      __builtin_bit_cast(bf16x8, a), __builtin_bit_cast(bf16x8, b), c, 0, 0, 0);
}

__device__ __forceinline__ int sigma_idx(int dir, int p){
  if (dir == 0) return p;
  if (dir == 1) return LTOT - 1 - p;
  return 4*(p % L4S) + (p / L4S);
}

__device__ __forceinline__ float silu_f(float x){
  return x / (1.f + __expf(-x));
}

// ---------------- LayerNorm: x (B,96,L) -> xnorm (B,L,96) ----------------
__global__ __launch_bounds__(256) void k_ln(const float* __restrict__ x,
    const float* __restrict__ g, const float* __restrict__ bt, float* __restrict__ xn)
{
  int i = blockIdx.x*256 + threadIdx.x;
  if (i >= BB*LTOT) return;
  int b = i / LTOT, ll = i % LTOT;
  const float* xp = x + (size_t)b*C0*LTOT + ll;
  float s = 0.f, ss = 0.f;
  for (int c = 0; c < C0; ++c){ float v = xp[(size_t)c*LTOT]; s += v; ss += v*v; }
  float mu = s * (1.f/C0);
  float var = ss * (1.f/C0) - mu*mu;
  float inv = rsqrtf(var + 1e-5f);
  float* op = xn + (size_t)i*C0;
  for (int c = 0; c < C0; ++c){
    float v = xp[(size_t)c*LTOT];
    op[c] = (v - mu)*inv*g[c] + bt[c];
  }
}

// ---------------- Generic tiled GEMM: O = A(MxK) * W(NxK)^T ----------------
// modes: 0 = in_proj split; 1 = plain; 2 = softplus+bias; 5 = bf16 store into
//        channel-last [row][96+col] of a 192-wide bf16 buffer
__global__ __launch_bounds__(256) void k_gemm(
    const float* __restrict__ A, const float* __restrict__ A2, const float* __restrict__ A3,
    int lda, const float* __restrict__ W, long wstride, const float* __restrict__ bias,
    int bias_stride, int N, int K, int rpb,
    float* __restrict__ O0, float* __restrict__ O1, int ldo, int mode)
{
  __shared__ float As[32][65];
  __shared__ float Ws[32][65];
  int tid = threadIdx.x;
  long row0 = (long)blockIdx.x * 64;
  int col0 = blockIdx.y * 64;
  int wb = (int)(row0 / rpb);
  const float* Wp = W + (long)wb * wstride;
  float acc[4][4] = {};
  int kk = tid & 31, rb = tid >> 5;
  int nk = (K + 31) >> 5;
  for (int kc = 0; kc < nk; ++kc){
    int k0 = kc*32;
    bool kin = (k0 + kk) < K;
    #pragma unroll
    for (int rr = 0; rr < 8; ++rr){
      int r = rb + rr*8;
      float a = 0.f;
      if (kin){
        long idx = (row0 + r)*(long)lda + k0 + kk;
        a = A[idx];
        if (A2) a += A2[idx] + A3[idx];
      }
      As[kk][r] = a;
      float wv = 0.f;
      if ((col0 + r) < N && kin) wv = Wp[(long)(col0 + r)*K + k0 + kk];
      Ws[kk][r] = wv;
    }
    __syncthreads();
    int r0 = (tid & 15)*4, c0 = (tid >> 4)*4;
    #pragma unroll
    for (int k = 0; k < 32; ++k){
      float av[4], wv[4];
      #pragma unroll
      for (int i = 0; i < 4; ++i){ av[i] = As[k][r0+i]; wv[i] = Ws[k][c0+i]; }
      #pragma unroll
      for (int i = 0; i < 4; ++i)
        #pragma unroll
        for (int j = 0; j < 4; ++j) acc[i][j] += av[i]*wv[j];
    }
    __syncthreads();
  }
  int r0 = (tid & 15)*4, c0 = (tid >> 4)*4;
  #pragma unroll
  for (int i = 0; i < 4; ++i){
    long row = row0 + r0 + i;
    #pragma unroll
    for (int j = 0; j < 4; ++j){
      int col = col0 + c0 + j;
      if (col >= N) continue;
      float v = acc[i][j];
      if (mode == 0){
        if (col < DINC) O0[row*DINC + col] = v;
        else            O1[row*DINC + col - DINC] = silu_f(v);
      } else if (mode == 1){
        O0[row*(long)ldo + col] = v;
      } else if (mode == 2){
        float xv = v + bias[wb*bias_stride + col];
        O0[row*(long)ldo + col] = (xv > 20.f) ? xv : log1pf(__expf(xv));
      } else if (mode == 5){
        ((__hip_bfloat16*)O0)[row*192 + 96 + col] = __float2bfloat16(v);
      }
    }
  }
}

// ---------------- depthwise causal conv1d (permuted) + SiLU ----------------
__global__ __launch_bounds__(256) void k_dwconv(const float* __restrict__ xin,
    const float* __restrict__ cw, const float* __restrict__ cb, float* __restrict__ u)
{
  long i = (long)blockIdx.x*256 + threadIdx.x;
  if (i >= 3L*BB*LTOT*DINC) return;
  int d = (int)(i % DINC); long t = i / DINC;
  int p = (int)(t % LTOT); t /= LTOT;
  int b = (int)(t % BB); int dir = (int)(t / BB);
  float acc = cb[dir*DINC + d];
  const float* wp = cw + ((long)dir*DINC + d)*4;
  #pragma unroll
  for (int kk = 0; kk < 4; ++kk){
    int pp = p - 3 + kk;
    if (pp >= 0){
      int l = sigma_idx(dir, pp);
      acc += xin[((long)b*LTOT + l)*DINC + d] * wp[kk];
    }
  }
  u[i] = silu_f(acc);
}

__global__ __launch_bounds__(256) void k_prepA(const float* __restrict__ al, float* __restrict__ A){
  int i = blockIdx.x*256 + threadIdx.x;
  if (i < 3*DINC*16) A[i] = -__expf(al[i]);
}

// ---------------- scan phase 1 ----------------
__global__ __launch_bounds__(256) void k_scan1(const float* __restrict__ u,
    const float* __restrict__ dt, const float* __restrict__ xdbl,
    const float* __restrict__ Abuf, float* __restrict__ aprod, float* __restrict__ hend)
{
  long i = (long)blockIdx.x*256 + threadIdx.x;
  int s = (int)(i & 15); long t = i >> 4;
  int d = (int)(t % DINC); t /= DINC;
  int c = (int)(t % NCHUNK); int bd = (int)(t / NCHUNK);
  int dir = bd >> 1;
  float Av = Abuf[((long)dir*DINC + d)*16 + s];
  long pbase = (long)bd*LTOT + (long)c*CLEN;
  float h = 0.f, ap = 1.f;
  for (int j = 0; j < CLEN; ++j){
    long p = pbase + j;
    float ldt = dt[p*DINC + d];
    float lu  = u [p*DINC + d];
    float bb  = xdbl[p*38 + 6 + s];
    float dA = __expf(ldt * Av);
    h = dA*h + ldt*lu*bb;
    ap *= dA;
  }
  long oi = (((long)bd*DINC + d)*NCHUNK + c)*16 + s;
  aprod[oi] = ap; hend[oi] = h;
}

// ---------------- scan phase 2 ----------------
__global__ __launch_bounds__(256) void k_scan2(float* __restrict__ aprod, const float* __restrict__ hend){
  long i = (long)blockIdx.x*256 + threadIdx.x;
  if (i >= 6L*DINC*16) return;
  int s = (int)(i & 15); long t = i >> 4;
  int d = (int)(t % DINC); int bd = (int)(t / DINC);
  long base = (((long)bd*DINC + d)*NCHUNK)*16 + s;
  float H = 0.f;
  for (int c = 0; c < NCHUNK; ++c){
    long idx = base + (long)c*16;
    float a = aprod[idx], he = hend[idx];
    aprod[idx] = H;
    H = he + a*H;
  }
}

// ---------------- scan phase 3 ----------------
__global__ __launch_bounds__(256) void k_scan3(const float* __restrict__ u,
    const float* __restrict__ dt, const float* __restrict__ xdbl,
    const float* __restrict__ Abuf, const float* __restrict__ hin,
    const float* __restrict__ Dp, const float* __restrict__ gate, float* __restrict__ qkv)
{
  int tid = threadIdx.x;
  int s = tid & 15, di = tid >> 4;
  int c  = blockIdx.x % NCHUNK;
  int dg = blockIdx.x / NCHUNK;
  int bd = blockIdx.y;
  int dir = bd >> 1, b = bd & 1;
  int d = dg*16 + di;
  float Av = Abuf[((long)dir*DINC + d)*16 + s];
  float Dv = Dp[dir*DINC + d];
  float h = hin[(((long)bd*DINC + d)*NCHUNK + c)*16 + s];
  long pbase = (long)bd*LTOT + (long)c*CLEN;
  for (int j = 0; j < CLEN; ++j){
    long p = pbase + j;
    float ldt = dt[p*DINC + d];
    float lu  = u [p*DINC + d];
    float bb  = xdbl[p*38 + 6  + s];
    float cc  = xdbl[p*38 + 22 + s];
    float dA = __expf(ldt * Av);
    h = dA*h + ldt*lu*bb;
    float yv = h*cc;
    yv += __shfl_xor(yv, 1);
    yv += __shfl_xor(yv, 2);
    yv += __shfl_xor(yv, 4);
    yv += __shfl_xor(yv, 8);
    if (s == 0){
      int pl = (int)(p - (long)bd*LTOT);
      int l = sigma_idx(dir, pl);
      long li = (long)b*LTOT + l;
      qkv[(((long)dir*BB + b)*LTOT + l)*DINC + d] = (yv + lu*Dv) * gate[li*DINC + d];
    }
  }
}

__global__ __launch_bounds__(256) void k_zero(float* __restrict__ p, int n){
  int i = blockIdx.x*256 + threadIdx.x;
  if (i < n) p[i] = 0.f;
}

// ---------------- attn_raw[b,d,e] += sum_l q[b,l,d] k[b,l,e] ----------------
__global__ __launch_bounds__(256) void k_qk(const float* __restrict__ q,
    const float* __restrict__ k, float* __restrict__ attn)
{
  __shared__ float Qs[32][64];
  __shared__ float Ks[32][64];
  int tid = threadIdx.x;
  int bx = blockIdx.x;
  int lc = bx % 24; int et = (bx/24) % 3; int dtl = (bx/72) % 3; int b = bx/216;
  long base = (long)b*LTOT;
  int l0 = lc*576;
  float acc[4][4] = {};
  int col = tid & 63, rbase = tid >> 6;
  for (int ls = 0; ls < 576; ls += 32){
    #pragma unroll
    for (int rr = 0; rr < 8; ++rr){
      int r = rbase + rr*4;
      long l = base + l0 + ls + r;
      Qs[r][col] = q[l*DINC + dtl*64 + col];
      Ks[r][col] = k[l*DINC + et *64 + col];
    }
    __syncthreads();
    int d0 = (tid & 15)*4, e0 = (tid >> 4)*4;
    #pragma unroll
    for (int ll = 0; ll < 32; ++ll){
      float qa[4], ka[4];
      #pragma unroll
      for (int i = 0; i < 4; ++i){ qa[i] = Qs[ll][d0+i]; ka[i] = Ks[ll][e0+i]; }
      #pragma unroll
      for (int i = 0; i < 4; ++i)
        #pragma unroll
        for (int j = 0; j < 4; ++j) acc[i][j] += qa[i]*ka[j];
    }
    __syncthreads();
  }
  int d0 = (tid & 15)*4, e0 = (tid >> 4)*4;
  #pragma unroll
  for (int i = 0; i < 4; ++i)
    #pragma unroll
    for (int j = 0; j < 4; ++j)
      atomicAdd(&attn[((long)b*DINC + dtl*64 + d0 + i)*DINC + et*64 + e0 + j], acc[i][j]);
}

__global__ __launch_bounds__(64) void k_softmax(float* __restrict__ attn){
  int row = blockIdx.x, tid = threadIdx.x;
  float* p = attn + (long)row*DINC;
  float v0 = p[tid], v1 = p[tid+64], v2 = p[tid+128];
  float m = fmaxf(v0, fmaxf(v1, v2));
  #pragma unroll
  for (int off = 32; off >= 1; off >>= 1) m = fmaxf(m, __shfl_xor(m, off));
  float e0 = __expf(v0-m), e1 = __expf(v1-m), e2 = __expf(v2-m);
  float s = e0 + e1 + e2;
  #pragma unroll
  for (int off = 32; off >= 1; off >>= 1) s += __shfl_xor(s, off);
  float inv = 1.f/s;
  p[tid] = e0*inv; p[tid+64] = e1*inv; p[tid+128] = e2*inv;
}

// ---------------- pack conv weights (96,192,27) f32 -> bf16 [t][oc][ic] ----------------
__global__ __launch_bounds__(256) void k_pack(const float* __restrict__ w1,
    const float* __restrict__ w2, __hip_bfloat16* __restrict__ p1, __hip_bfloat16* __restrict__ p2)
{
  int i = blockIdx.x*256 + threadIdx.x;
  if (i >= 2*497664) return;
  int which = i / 497664; int r = i % 497664;
  int ic = r % 192; int oc = (r/192) % 96; int t = r/(192*96);
  const float* w = which ? w2 : w1;
  float v = w[(long)oc*5184 + ic*27 + t];
  (which ? p2 : p1)[r] = __float2bfloat16(v);
}

// ---------------- transpose viewed (B,192,13824) f32 -> bf16 [b][sp][192] ----------------
__global__ __launch_bounds__(256) void k_trans(const float* __restrict__ src,
    __hip_bfloat16* __restrict__ dst)
{
  __shared__ float lds[32][33];
  int tx = threadIdx.x & 31, ty = threadIdx.x >> 5;
  int sb = blockIdx.x*32;           // sp tile
  int cb = blockIdx.y*32;           // channel tile
  int b  = blockIdx.z;
  const float* s = src + (long)b*2654208;
  #pragma unroll
  for (int j = 0; j < 4; ++j)
    lds[ty + j*8][tx] = s[(long)(cb + ty + j*8)*13824 + sb + tx];
  __syncthreads();
  #pragma unroll
  for (int j = 0; j < 4; ++j)
    dst[((long)b*13824 + sb + ty + j*8)*192 + cb + tx] = __float2bfloat16(lds[tx][ty + j*8]);
}

// ---------------- conv1 MFMA: rows=oc(96), cols=sp; partials per kd-group ----------------
__global__ __launch_bounds__(256) void k_convm1(const __hip_bfloat16* __restrict__ inT,
    const __hip_bfloat16* __restrict__ Wp, float* __restrict__ pbuf)
{
  int wv = blockIdx.x*4 + (threadIdx.x >> 6);     // 0..2591
  int lane = threadIdx.x & 63;
  int st = wv % 432;
  int b  = (wv / 432) % 2;
  int g  = wv / 864;                               // kd = g-1
  int sp0 = st*32;
  int lr = lane & 15, lk = lane >> 4;
  const s16x8 zer = {0,0,0,0,0,0,0,0};
  f32x4 acc[6][2];
  #pragma unroll
  for (int i = 0; i < 6; ++i){ acc[i][0] = f32x4{0.f,0.f,0.f,0.f}; acc[i][1] = f32x4{0.f,0.f,0.f,0.f}; }
  int kd = g - 1;
  int spc[2], hh[2], wwv[2], zzv[2]; bool hok[2];
  #pragma unroll
  for (int c = 0; c < 2; ++c){
    int sp = sp0 + c*16 + lr;
    spc[c] = sp; hh[c] = sp/576; wwv[c] = (sp/24)%24; zzv[c] = sp%24;
    hok[c] = (unsigned)(hh[c] + kd) < 24u;
  }
  for (int t = 0; t < 9; ++t){
    int dw = t/3 - 1, dz = t%3 - 1;
    int tg = g*9 + t;
    bool ok[2]; const __hip_bfloat16* bp[2];
    #pragma unroll
    for (int c = 0; c < 2; ++c){
      ok[c] = hok[c] && ((unsigned)(wwv[c]+dw) < 24u) && ((unsigned)(zzv[c]+dz) < 24u);
      int spp = spc[c] + kd*576 + dw*24 + dz;
      spp = min(13823, max(0, spp));
      bp[c] = inT + ((long)(b*13824 + spp)*192 + lk*8);
    }
    const __hip_bfloat16* ap = Wp + ((long)(tg*96 + lr)*192 + lk*8);
    for (int kc = 0; kc < 6; ++kc){
      s16x8 b0 = ok[0] ? *(const s16x8*)(bp[0] + kc*32) : zer;
      s16x8 b1 = ok[1] ? *(const s16x8*)(bp[1] + kc*32) : zer;
      #pragma unroll
      for (int rf = 0; rf < 6; ++rf){
        s16x8 a = *(const s16x8*)(ap + rf*16*192 + kc*32);
        acc[rf][0] = mfma16(a, b0, acc[rf][0]);
        acc[rf][1] = mfma16(a, b1, acc[rf][1]);
      }
    }
  }
  // D: col = sp = sp0+c*16+lr, row = oc = rf*16 + lk*4 + reg
  #pragma unroll
  for (int rf = 0; rf < 6; ++rf)
    #pragma unroll
    for (int c = 0; c < 2; ++c){
      int sp = sp0 + c*16 + lr;
      int oc0 = rf*16 + lk*4;
      *reinterpret_cast<f32x4*>(pbuf + ((long)(g*2 + b)*13824 + sp)*96 + oc0) = acc[rf][c];
    }
}

// ---------------- reduce conv1 partials + bias -> bf16 inT2[.][0..96) ----------------
__global__ __launch_bounds__(256) void k_red1(const float* __restrict__ pbuf,
    const float* __restrict__ bias, __hip_bfloat16* __restrict__ inT2)
{
  int i = blockIdx.x*256 + threadIdx.x;           // (b*13824+sp)*96+oc
  if (i >= 2654208) return;
  int oc = i % 96;
  float v = pbuf[i] + pbuf[2654208 + i] + pbuf[2*2654208 + i] + bias[oc];
  long row = i / 96;
  inT2[row*192 + oc] = __float2bfloat16(v);
}

// ---------------- conv2 MFMA: rows=sp, cols=oc(96); partials per kd-group ----------------
__global__ __launch_bounds__(256) void k_convm2(const __hip_bfloat16* __restrict__ inT,
    const __hip_bfloat16* __restrict__ Wp, float* __restrict__ pbuf)
{
  int wv = blockIdx.x*4 + (threadIdx.x >> 6);
  int lane = threadIdx.x & 63;
  int st = wv % 432;
  int b  = (wv / 432) % 2;
  int g  = wv / 864;
  int sp0 = st*32;
  int lr = lane & 15, lk = lane >> 4;
  const s16x8 zer = {0,0,0,0,0,0,0,0};
  f32x4 acc[2][6];
  #pragma unroll
  for (int r = 0; r < 2; ++r)
    #pragma unroll
    for (int c = 0; c < 6; ++c) acc[r][c] = f32x4{0.f,0.f,0.f,0.f};
  int kd = g - 1;
  int spr[2], hh[2], wwv[2], zzv[2]; bool hok[2];
  #pragma unroll
  for (int r = 0; r < 2; ++r){
    int sp = sp0 + r*16 + lr;
    spr[r] = sp; hh[r] = sp/576; wwv[r] = (sp/24)%24; zzv[r] = sp%24;
    hok[r] = (unsigned)(hh[r] + kd) < 24u;
  }
  for (int t = 0; t < 9; ++t){
    int dw = t/3 - 1, dz = t%3 - 1;
    int tg = g*9 + t;
    bool ok[2]; const __hip_bfloat16* ap[2];
    #pragma unroll
    for (int r = 0; r < 2; ++r){
      ok[r] = hok[r] && ((unsigned)(wwv[r]+dw) < 24u) && ((unsigned)(zzv[r]+dz) < 24u);
      int spp = spr[r] + kd*576 + dw*24 + dz;
      spp = min(13823, max(0, spp));
      ap[r] = inT + ((long)(b*13824 + spp)*192 + lk*8);
    }
    const __hip_bfloat16* bp = Wp + ((long)(tg*96 + lr)*192 + lk*8);
    for (int kc = 0; kc < 6; ++kc){
      s16x8 a0 = ok[0] ? *(const s16x8*)(ap[0] + kc*32) : zer;
      s16x8 a1 = ok[1] ? *(const s16x8*)(ap[1] + kc*32) : zer;
      #pragma unroll
      for (int cf = 0; cf < 6; ++cf){
        s16x8 bb = *(const s16x8*)(bp + cf*16*192 + kc*32);
        acc[0][cf] = mfma16(a0, bb, acc[0][cf]);
        acc[1][cf] = mfma16(a1, bb, acc[1][cf]);
      }
    }
  }
  // D: col = oc = cf*16+lr, row = sp = sp0 + r*16 + lk*4 + reg
  #pragma unroll
  for (int r = 0; r < 2; ++r)
    #pragma unroll
    for (int cf = 0; cf < 6; ++cf){
      int oc = cf*16 + lr;
      int sprow = sp0 + r*16 + lk*4;
      *reinterpret_cast<f32x4*>(pbuf + ((long)(g*2 + b)*96 + oc)*13824 + sprow) = acc[r][cf];
    }
}

// ---------------- reduce conv2 partials + bias + x -> d_out ----------------
__global__ __launch_bounds__(256) void k_red2(const float* __restrict__ pbuf,
    const float* __restrict__ bias, const float* __restrict__ x, float* __restrict__ out)
{
  int i = blockIdx.x*256 + threadIdx.x;           // (b*96+oc)*13824+sp
  if (i >= 2654208) return;
  int oc = (i / 13824) % 96;
  out[i] = pbuf[i] + pbuf[2654208 + i] + pbuf[2*2654208 + i] + bias[oc] + x[i];
}

extern "C" void kernel_launch(void* const* d_in, const int* in_sizes, int n_in,
                              void* d_out, int out_size, void* d_ws, size_t ws_size,
                              hipStream_t stream)
{
  const float* x          = (const float*)d_in[0];
  const float* ln_g       = (const float*)d_in[1];
  const float* ln_b       = (const float*)d_in[2];
  const float* in_proj_w  = (const float*)d_in[3];
  const float* conv_w     = (const float*)d_in[4];
  const float* conv_b     = (const float*)d_in[5];
  const float* xproj_w    = (const float*)d_in[6];
  const float* dt_w       = (const float*)d_in[7];
  const float* dt_b       = (const float*)d_in[8];
  const float* A_log      = (const float*)d_in[9];
  const float* Dp         = (const float*)d_in[10];
  const float* out_proj_w = (const float*)d_in[11];
  const float* f1_w       = (const float*)d_in[12];
  const float* f1_b       = (const float*)d_in[13];
  const float* f2_w       = (const float*)d_in[14];
  const float* f2_b       = (const float*)d_in[15];
  float* out = (float*)d_out;

  const size_t BL = (size_t)BB*LTOT;
  const size_t S  = BL*DINC;

  void* wsp = nullptr;
  (void)hipGetSymbolAddress(&wsp, HIP_SYMBOL(g_ws));
  float* ws = (float*)wsp;
  size_t off = 0;
  auto alloc = [&](size_t n){ float* p = ws + off; off += n; return p; };
  float* xnorm = alloc(BL*C0);
  float* xin   = alloc(S);
  float* gate  = alloc(S);
  float* u     = alloc(3*S);
  float* dtb   = alloc(3*S);
  float* xdbl  = alloc(3*BL*38);
  float* qkv   = alloc(3*S);
  float* Abuf  = alloc(3*DINC*16);
  float* aprod = alloc((size_t)6*DINC*16*NCHUNK);
  float* hend  = alloc((size_t)6*DINC*16*NCHUNK);
  float* attn  = alloc((size_t)BB*DINC*DINC);
  float* outa  = alloc(S);
  float* pbuf  = alloc((size_t)3*2654208);                 // shared by conv1/conv2
  __hip_bfloat16* inT1 = (__hip_bfloat16*)alloc(2654208);  // [b][sp][192] bf16
  __hip_bfloat16* inT2 = (__hip_bfloat16*)alloc(2654208);
  __hip_bfloat16* Wp1  = (__hip_bfloat16*)alloc(248832);   // [27][96][192] bf16
  __hip_bfloat16* Wp2  = (__hip_bfloat16*)alloc(248832);

  // 0) pack conv weights to bf16
  k_pack<<<3888, 256, 0, stream>>>(f1_w, f2_w, Wp1, Wp2);
  // 1) layernorm + transpose
  k_ln<<<108, 256, 0, stream>>>(x, ln_g, ln_b, xnorm);
  // 2) in_proj -> xin + silu gate
  k_gemm<<<dim3(432, 6), 256, 0, stream>>>(xnorm, nullptr, nullptr, 96,
      in_proj_w, 0, nullptr, 0, 384, 96, (int)BL, xin, gate, DINC, 0);
  // 3) depthwise causal conv + silu
  k_dwconv<<<62208, 256, 0, stream>>>(xin, conv_w, conv_b, u);
  // 4) xproj
  k_gemm<<<dim3(1296, 1), 256, 0, stream>>>(u, nullptr, nullptr, DINC,
      xproj_w, 38L*192, nullptr, 0, 38, 192, (int)BL, xdbl, nullptr, 38, 1);
  // 5) dt proj + softplus
  k_gemm<<<dim3(1296, 3), 256, 0, stream>>>(xdbl, nullptr, nullptr, 38,
      dt_w, 192L*6, dt_b, 192, 192, 6, (int)BL, dtb, nullptr, DINC, 2);
  // 6) A = -exp(A_log)
  k_prepA<<<36, 256, 0, stream>>>(A_log, Abuf);
  // 7) chunked selective scan
  k_scan1<<<7776, 256, 0, stream>>>(u, dtb, xdbl, Abuf, aprod, hend);
  k_scan2<<<72, 256, 0, stream>>>(aprod, hend);
  k_scan3<<<dim3(NCHUNK*12, 6), 256, 0, stream>>>(u, dtb, xdbl, Abuf, aprod, Dp, gate, qkv);
  // 8) attention matrix + softmax
  k_zero<<<288, 256, 0, stream>>>(attn, BB*DINC*DINC);
  k_qk<<<432, 256, 0, stream>>>(qkv, qkv + S, attn);
  k_softmax<<<BB*DINC, 64, 0, stream>>>(attn);
  // 9) out_a = v @ attn^T -> f32 (B,L,192)
  k_gemm<<<dim3(432, 3), 256, 0, stream>>>(qkv + 2*S, nullptr, nullptr, DINC,
      attn, (long)DINC*DINC, nullptr, 0, DINC, DINC, LTOT, outa, nullptr, DINC, 1);
  // 10) out_m = (q+k+v) @ out_proj^T -> bf16 into inT2[.][96..192)
  k_gemm<<<dim3(432, 2), 256, 0, stream>>>(qkv, qkv + S, qkv + 2*S, DINC,
      out_proj_w, 0, nullptr, 0, 96, 192, LTOT, (float*)inT2, nullptr, 0, 5);
  // 11) transpose viewed out_a to channel-last bf16
  k_trans<<<dim3(432, 6, 2), 256, 0, stream>>>(outa, inT1);
  // 12) conv3d #1 via MFMA, 3 kd-group partials, reduce -> inT2[.][0..96)
  k_convm1<<<648, 256, 0, stream>>>(inT1, Wp1, pbuf);
  k_red1<<<10368, 256, 0, stream>>>(pbuf, f1_b, inT2);
  // 13) conv3d #2 via MFMA -> partials, reduce + bias + x -> d_out
  k_convm2<<<648, 256, 0, stream>>>(inT2, Wp2, pbuf);
  k_red2<<<10368, 256, 0, stream>>>(pbuf, f2_b, x, out);
}

// Round 5
// 1011.192 us; speedup vs baseline: 3.7126x; 1.3775x over previous
//
#include <hip/hip_runtime.h>
#include <hip/hip_bf16.h>
#include <math.h>

#define BB 2
#define C0 96
#define LTOT 13824
#define DINC 192
#define L4S 3456
#define NCHUNK 216
#define CLEN 64

// Static device workspace (~368 MB .bss)
#define WS_FLOATS 92000000
__device__ __attribute__((aligned(256))) float g_ws[WS_FLOATS];

typedef __bf16 bf16x8 __attribute__((ext_vector_type(8)));
typedef short  s16x8  __attribute__((ext_vector_type(8)));
typedef float  f32x4  __attribute__((ext_vector_type(4)));

__device__ __forceinline__ f32x4 mfma16(s16x8 a, s16x8 b, f32x4 c){
  return __builtin_amdgcn_mfma_f32_16x16x32_bf16(
      __builtin_bit_cast(bf16x8, a), __builtin_bit_cast(bf16x8, b), c, 0, 0, 0);
}

__device__ __forceinline__ int sigma_idx(int dir, int p){
  if (dir == 0) return p;
  if (dir == 1) return LTOT - 1 - p;
  return 4*(p % L4S) + (p / L4S);
}

__device__ __forceinline__ float silu_f(float x){
  return x / (1.f + __expf(-x));
}

// ---------------- LayerNorm: x (B,96,L) -> xnorm (B,L,96) ----------------
__global__ __launch_bounds__(256) void k_ln(const float* __restrict__ x,
    const float* __restrict__ g, const float* __restrict__ bt, float* __restrict__ xn)
{
  int i = blockIdx.x*256 + threadIdx.x;
  if (i >= BB*LTOT) return;
  int b = i / LTOT, ll = i % LTOT;
  const float* xp = x + (size_t)b*C0*LTOT + ll;
  float s = 0.f, ss = 0.f;
  for (int c = 0; c < C0; ++c){ float v = xp[(size_t)c*LTOT]; s += v; ss += v*v; }
  float mu = s * (1.f/C0);
  float var = ss * (1.f/C0) - mu*mu;
  float inv = rsqrtf(var + 1e-5f);
  float* op = xn + (size_t)i*C0;
  for (int c = 0; c < C0; ++c){
    float v = xp[(size_t)c*LTOT];
    op[c] = (v - mu)*inv*g[c] + bt[c];
  }
}

// ---------------- Generic tiled GEMM: O = A(MxK) * W(NxK)^T ----------------
__global__ __launch_bounds__(256) void k_gemm(
    const float* __restrict__ A, const float* __restrict__ A2, const float* __restrict__ A3,
    int lda, const float* __restrict__ W, long wstride, const float* __restrict__ bias,
    int bias_stride, int N, int K, int rpb,
    float* __restrict__ O0, float* __restrict__ O1, int ldo, int mode)
{
  __shared__ float As[32][65];
  __shared__ float Ws[32][65];
  int tid = threadIdx.x;
  long row0 = (long)blockIdx.x * 64;
  int col0 = blockIdx.y * 64;
  int wb = (int)(row0 / rpb);
  const float* Wp = W + (long)wb * wstride;
  float acc[4][4] = {};
  int kk = tid & 31, rb = tid >> 5;
  int nk = (K + 31) >> 5;
  for (int kc = 0; kc < nk; ++kc){
    int k0 = kc*32;
    bool kin = (k0 + kk) < K;
    #pragma unroll
    for (int rr = 0; rr < 8; ++rr){
      int r = rb + rr*8;
      float a = 0.f;
      if (kin){
        long idx = (row0 + r)*(long)lda + k0 + kk;
        a = A[idx];
        if (A2) a += A2[idx] + A3[idx];
      }
      As[kk][r] = a;
      float wv = 0.f;
      if ((col0 + r) < N && kin) wv = Wp[(long)(col0 + r)*K + k0 + kk];
      Ws[kk][r] = wv;
    }
    __syncthreads();
    int r0 = (tid & 15)*4, c0 = (tid >> 4)*4;
    #pragma unroll
    for (int k = 0; k < 32; ++k){
      float av[4], wv[4];
      #pragma unroll
      for (int i = 0; i < 4; ++i){ av[i] = As[k][r0+i]; wv[i] = Ws[k][c0+i]; }
      #pragma unroll
      for (int i = 0; i < 4; ++i)
        #pragma unroll
        for (int j = 0; j < 4; ++j) acc[i][j] += av[i]*wv[j];
    }
    __syncthreads();
  }
  int r0 = (tid & 15)*4, c0 = (tid >> 4)*4;
  #pragma unroll
  for (int i = 0; i < 4; ++i){
    long row = row0 + r0 + i;
    #pragma unroll
    for (int j = 0; j < 4; ++j){
      int col = col0 + c0 + j;
      if (col >= N) continue;
      float v = acc[i][j];
      if (mode == 0){
        if (col < DINC) O0[row*DINC + col] = v;
        else            O1[row*DINC + col - DINC] = silu_f(v);
      } else if (mode == 1){
        O0[row*(long)ldo + col] = v;
      } else if (mode == 2){
        float xv = v + bias[wb*bias_stride + col];
        O0[row*(long)ldo + col] = (xv > 20.f) ? xv : log1pf(__expf(xv));
      } else if (mode == 5){
        ((__hip_bfloat16*)O0)[row*192 + 96 + col] = __float2bfloat16(v);
      }
    }
  }
}

// ---------------- depthwise causal conv1d (permuted) + SiLU ----------------
__global__ __launch_bounds__(256) void k_dwconv(const float* __restrict__ xin,
    const float* __restrict__ cw, const float* __restrict__ cb, float* __restrict__ u)
{
  long i = (long)blockIdx.x*256 + threadIdx.x;
  if (i >= 3L*BB*LTOT*DINC) return;
  int d = (int)(i % DINC); long t = i / DINC;
  int p = (int)(t % LTOT); t /= LTOT;
  int b = (int)(t % BB); int dir = (int)(t / BB);
  float acc = cb[dir*DINC + d];
  const float* wp = cw + ((long)dir*DINC + d)*4;
  #pragma unroll
  for (int kk = 0; kk < 4; ++kk){
    int pp = p - 3 + kk;
    if (pp >= 0){
      int l = sigma_idx(dir, pp);
      acc += xin[((long)b*LTOT + l)*DINC + d] * wp[kk];
    }
  }
  u[i] = silu_f(acc);
}

__global__ __launch_bounds__(256) void k_prepA(const float* __restrict__ al, float* __restrict__ A){
  int i = blockIdx.x*256 + threadIdx.x;
  if (i < 3*DINC*16) A[i] = -__expf(al[i]);
}

// ---------------- scan phase 1: per-chunk local scan, 16 s-states in regs ----------------
__global__ __launch_bounds__(192) void k_scan1(const float* __restrict__ u,
    const float* __restrict__ dt, const float* __restrict__ xdbl,
    const float* __restrict__ Abuf, float* __restrict__ aprod, float* __restrict__ hend)
{
  __shared__ float sB[CLEN][16];
  int d = threadIdx.x;
  int c  = blockIdx.x % NCHUNK;
  int bd = blockIdx.x / NCHUNK;
  int dir = bd >> 1;
  long pbase = (long)bd*LTOT + (long)c*CLEN;
  for (int idx = d; idx < CLEN*16; idx += 192){
    int j = idx >> 4, s = idx & 15;
    sB[j][s] = xdbl[(pbase + j)*38 + 6 + s];
  }
  __syncthreads();
  float A[16], h[16];
  #pragma unroll
  for (int s = 0; s < 16; ++s){
    A[s] = Abuf[((long)dir*DINC + d)*16 + s];
    h[s] = 0.f;
  }
  float sum_dt = 0.f;
  for (int j = 0; j < CLEN; ++j){
    long p = pbase + j;
    float ldt = dt[p*DINC + d];
    float lu  = u [p*DINC + d];
    sum_dt += ldt;
    float du = ldt*lu;
    #pragma unroll
    for (int s = 0; s < 16; ++s){
      float dA = __expf(ldt * A[s]);
      h[s] = dA*h[s] + du*sB[j][s];
    }
  }
  long oi = (((long)bd*DINC + d)*NCHUNK + c)*16;
  #pragma unroll
  for (int s = 0; s < 16; ++s){
    aprod[oi + s] = __expf(A[s]*sum_dt);
    hend [oi + s] = h[s];
  }
}

// ---------------- scan phase 2: scan over chunks; aprod becomes h_in ----------------
__global__ __launch_bounds__(256) void k_scan2(float* __restrict__ aprod, const float* __restrict__ hend){
  long i = (long)blockIdx.x*256 + threadIdx.x;
  if (i >= 6L*DINC*16) return;
  int s = (int)(i & 15); long t = i >> 4;
  int d = (int)(t % DINC); int bd = (int)(t / DINC);
  long base = (((long)bd*DINC + d)*NCHUNK)*16 + s;
  float H = 0.f;
  for (int c = 0; c < NCHUNK; ++c){
    long idx = base + (long)c*16;
    float a = aprod[idx], he = hend[idx];
    aprod[idx] = H;
    H = he + a*H;
  }
}

// ---------------- scan phase 3: recompute with h_in, y-dot in regs, gate+inv-perm ----------------
__global__ __launch_bounds__(192) void k_scan3(const float* __restrict__ u,
    const float* __restrict__ dt, const float* __restrict__ xdbl,
    const float* __restrict__ Abuf, const float* __restrict__ hin,
    const float* __restrict__ Dp, const float* __restrict__ gate, float* __restrict__ qkv)
{
  __shared__ float sB[CLEN][16];
  __shared__ float sC[CLEN][16];
  int d = threadIdx.x;
  int c  = blockIdx.x % NCHUNK;
  int bd = blockIdx.x / NCHUNK;
  int dir = bd >> 1, b = bd & 1;
  long pbase = (long)bd*LTOT + (long)c*CLEN;
  for (int idx = d; idx < CLEN*16; idx += 192){
    int j = idx >> 4, s = idx & 15;
    sB[j][s] = xdbl[(pbase + j)*38 + 6  + s];
    sC[j][s] = xdbl[(pbase + j)*38 + 22 + s];
  }
  __syncthreads();
  float A[16], h[16];
  long oi = (((long)bd*DINC + d)*NCHUNK + c)*16;
  #pragma unroll
  for (int s = 0; s < 16; ++s){
    A[s] = Abuf[((long)dir*DINC + d)*16 + s];
    h[s] = hin[oi + s];
  }
  float Dv = Dp[dir*DINC + d];
  for (int j = 0; j < CLEN; ++j){
    long p = pbase + j;
    float ldt = dt[p*DINC + d];
    float lu  = u [p*DINC + d];
    float du = ldt*lu;
    float y = 0.f;
    #pragma unroll
    for (int s = 0; s < 16; ++s){
      float dA = __expf(ldt * A[s]);
      h[s] = dA*h[s] + du*sB[j][s];
      y += h[s]*sC[j][s];
    }
    int pl = c*CLEN + j;
    int l = sigma_idx(dir, pl);
    long li = (long)b*LTOT + l;
    qkv[(((long)dir*BB + b)*LTOT + l)*DINC + d] = (y + lu*Dv) * gate[li*DINC + d];
  }
}

__global__ __launch_bounds__(256) void k_zero(float* __restrict__ p, int n){
  int i = blockIdx.x*256 + threadIdx.x;
  if (i < n) p[i] = 0.f;
}

// ---------------- attn_raw[b,d,e] += sum_l q[b,l,d] k[b,l,e] ----------------
__global__ __launch_bounds__(256) void k_qk(const float* __restrict__ q,
    const float* __restrict__ k, float* __restrict__ attn)
{
  __shared__ float Qs[32][64];
  __shared__ float Ks[32][64];
  int tid = threadIdx.x;
  int bx = blockIdx.x;
  int lc = bx % 24; int et = (bx/24) % 3; int dtl = (bx/72) % 3; int b = bx/216;
  long base = (long)b*LTOT;
  int l0 = lc*576;
  float acc[4][4] = {};
  int col = tid & 63, rbase = tid >> 6;
  for (int ls = 0; ls < 576; ls += 32){
    #pragma unroll
    for (int rr = 0; rr < 8; ++rr){
      int r = rbase + rr*4;
      long l = base + l0 + ls + r;
      Qs[r][col] = q[l*DINC + dtl*64 + col];
      Ks[r][col] = k[l*DINC + et *64 + col];
    }
    __syncthreads();
    int d0 = (tid & 15)*4, e0 = (tid >> 4)*4;
    #pragma unroll
    for (int ll = 0; ll < 32; ++ll){
      float qa[4], ka[4];
      #pragma unroll
      for (int i = 0; i < 4; ++i){ qa[i] = Qs[ll][d0+i]; ka[i] = Ks[ll][e0+i]; }
      #pragma unroll
      for (int i = 0; i < 4; ++i)
        #pragma unroll
        for (int j = 0; j < 4; ++j) acc[i][j] += qa[i]*ka[j];
    }
    __syncthreads();
  }
  int d0 = (tid & 15)*4, e0 = (tid >> 4)*4;
  #pragma unroll
  for (int i = 0; i < 4; ++i)
    #pragma unroll
    for (int j = 0; j < 4; ++j)
      atomicAdd(&attn[((long)b*DINC + dtl*64 + d0 + i)*DINC + et*64 + e0 + j], acc[i][j]);
}

__global__ __launch_bounds__(64) void k_softmax(float* __restrict__ attn){
  int row = blockIdx.x, tid = threadIdx.x;
  float* p = attn + (long)row*DINC;
  float v0 = p[tid], v1 = p[tid+64], v2 = p[tid+128];
  float m = fmaxf(v0, fmaxf(v1, v2));
  #pragma unroll
  for (int off = 32; off >= 1; off >>= 1) m = fmaxf(m, __shfl_xor(m, off));
  float e0 = __expf(v0-m), e1 = __expf(v1-m), e2 = __expf(v2-m);
  float s = e0 + e1 + e2;
  #pragma unroll
  for (int off = 32; off >= 1; off >>= 1) s += __shfl_xor(s, off);
  float inv = 1.f/s;
  p[tid] = e0*inv; p[tid+64] = e1*inv; p[tid+128] = e2*inv;
}

// ---------------- pack conv weights (96,192,27) f32 -> bf16 [t][oc][ic] ----------------
__global__ __launch_bounds__(256) void k_pack(const float* __restrict__ w1,
    const float* __restrict__ w2, __hip_bfloat16* __restrict__ p1, __hip_bfloat16* __restrict__ p2)
{
  int i = blockIdx.x*256 + threadIdx.x;
  if (i >= 2*497664) return;
  int which = i / 497664; int r = i % 497664;
  int ic = r % 192; int oc = (r/192) % 96; int t = r/(192*96);
  const float* w = which ? w2 : w1;
  float v = w[(long)oc*5184 + ic*27 + t];
  (which ? p2 : p1)[r] = __float2bfloat16(v);
}

// ---------------- transpose viewed (B,192,13824) f32 -> bf16 [b][sp][192] ----------------
__global__ __launch_bounds__(256) void k_trans(const float* __restrict__ src,
    __hip_bfloat16* __restrict__ dst)
{
  __shared__ float lds[32][33];
  int tx = threadIdx.x & 31, ty = threadIdx.x >> 5;
  int sb = blockIdx.x*32;
  int cb = blockIdx.y*32;
  int b  = blockIdx.z;
  const float* s = src + (long)b*2654208;
  #pragma unroll
  for (int j = 0; j < 4; ++j)
    lds[ty + j*8][tx] = s[(long)(cb + ty + j*8)*13824 + sb + tx];
  __syncthreads();
  #pragma unroll
  for (int j = 0; j < 4; ++j)
    dst[((long)b*13824 + sb + ty + j*8)*192 + cb + tx] = __float2bfloat16(lds[tx][ty + j*8]);
}

// ---------------- conv1 MFMA: rows=oc(96), cols=sp; partials per kd-group ----------------
__global__ __launch_bounds__(256) void k_convm1(const __hip_bfloat16* __restrict__ inT,
    const __hip_bfloat16* __restrict__ Wp, float* __restrict__ pbuf)
{
  int wv = blockIdx.x*4 + (threadIdx.x >> 6);
  int lane = threadIdx.x & 63;
  int st = wv % 432;
  int b  = (wv / 432) % 2;
  int g  = wv / 864;
  int sp0 = st*32;
  int lr = lane & 15, lk = lane >> 4;
  const s16x8 zer = {0,0,0,0,0,0,0,0};
  f32x4 acc[6][2];
  #pragma unroll
  for (int i = 0; i < 6; ++i){ acc[i][0] = f32x4{0.f,0.f,0.f,0.f}; acc[i][1] = f32x4{0.f,0.f,0.f,0.f}; }
  int kd = g - 1;
  int spc[2], hh[2], wwv[2], zzv[2]; bool hok[2];
  #pragma unroll
  for (int c = 0; c < 2; ++c){
    int sp = sp0 + c*16 + lr;
    spc[c] = sp; hh[c] = sp/576; wwv[c] = (sp/24)%24; zzv[c] = sp%24;
    hok[c] = (unsigned)(hh[c] + kd) < 24u;
  }
  for (int t = 0; t < 9; ++t){
    int dw = t/3 - 1, dz = t%3 - 1;
    int tg = g*9 + t;
    bool ok[2]; const __hip_bfloat16* bp[2];
    #pragma unroll
    for (int c = 0; c < 2; ++c){
      ok[c] = hok[c] && ((unsigned)(wwv[c]+dw) < 24u) && ((unsigned)(zzv[c]+dz) < 24u);
      int spp = spc[c] + kd*576 + dw*24 + dz;
      spp = min(13823, max(0, spp));
      bp[c] = inT + ((long)(b*13824 + spp)*192 + lk*8);
    }
    const __hip_bfloat16* ap = Wp + ((long)(tg*96 + lr)*192 + lk*8);
    for (int kc = 0; kc < 6; ++kc){
      s16x8 b0 = ok[0] ? *(const s16x8*)(bp[0] + kc*32) : zer;
      s16x8 b1 = ok[1] ? *(const s16x8*)(bp[1] + kc*32) : zer;
      #pragma unroll
      for (int rf = 0; rf < 6; ++rf){
        s16x8 a = *(const s16x8*)(ap + rf*16*192 + kc*32);
        acc[rf][0] = mfma16(a, b0, acc[rf][0]);
        acc[rf][1] = mfma16(a, b1, acc[rf][1]);
      }
    }
  }
  #pragma unroll
  for (int rf = 0; rf < 6; ++rf)
    #pragma unroll
    for (int c = 0; c < 2; ++c){
      int sp = sp0 + c*16 + lr;
      int oc0 = rf*16 + lk*4;
      *reinterpret_cast<f32x4*>(pbuf + ((long)(g*2 + b)*13824 + sp)*96 + oc0) = acc[rf][c];
    }
}

// ---------------- reduce conv1 partials + bias -> bf16 inT2[.][0..96) ----------------
__global__ __launch_bounds__(256) void k_red1(const float* __restrict__ pbuf,
    const float* __restrict__ bias, __hip_bfloat16* __restrict__ inT2)
{
  int i = blockIdx.x*256 + threadIdx.x;
  if (i >= 2654208) return;
  int oc = i % 96;
  float v = pbuf[i] + pbuf[2654208 + i] + pbuf[2*2654208 + i] + bias[oc];
  long row = i / 96;
  inT2[row*192 + oc] = __float2bfloat16(v);
}

// ---------------- conv2 MFMA: rows=sp, cols=oc(96); partials per kd-group ----------------
__global__ __launch_bounds__(256) void k_convm2(const __hip_bfloat16* __restrict__ inT,
    const __hip_bfloat16* __restrict__ Wp, float* __restrict__ pbuf)
{
  int wv = blockIdx.x*4 + (threadIdx.x >> 6);
  int lane = threadIdx.x & 63;
  int st = wv % 432;
  int b  = (wv / 432) % 2;
  int g  = wv / 864;
  int sp0 = st*32;
  int lr = lane & 15, lk = lane >> 4;
  const s16x8 zer = {0,0,0,0,0,0,0,0};
  f32x4 acc[2][6];
  #pragma unroll
  for (int r = 0; r < 2; ++r)
    #pragma unroll
    for (int c = 0; c < 6; ++c) acc[r][c] = f32x4{0.f,0.f,0.f,0.f};
  int kd = g - 1;
  int spr[2], hh[2], wwv[2], zzv[2]; bool hok[2];
  #pragma unroll
  for (int r = 0; r < 2; ++r){
    int sp = sp0 + r*16 + lr;
    spr[r] = sp; hh[r] = sp/576; wwv[r] = (sp/24)%24; zzv[r] = sp%24;
    hok[r] = (unsigned)(hh[r] + kd) < 24u;
  }
  for (int t = 0; t < 9; ++t){
    int dw = t/3 - 1, dz = t%3 - 1;
    int tg = g*9 + t;
    bool ok[2]; const __hip_bfloat16* ap[2];
    #pragma unroll
    for (int r = 0; r < 2; ++r){
      ok[r] = hok[r] && ((unsigned)(wwv[r]+dw) < 24u) && ((unsigned)(zzv[r]+dz) < 24u);
      int spp = spr[r] + kd*576 + dw*24 + dz;
      spp = min(13823, max(0, spp));
      ap[r] = inT + ((long)(b*13824 + spp)*192 + lk*8);
    }
    const __hip_bfloat16* bp = Wp + ((long)(tg*96 + lr)*192 + lk*8);
    for (int kc = 0; kc < 6; ++kc){
      s16x8 a0 = ok[0] ? *(const s16x8*)(ap[0] + kc*32) : zer;
      s16x8 a1 = ok[1] ? *(const s16x8*)(ap[1] + kc*32) : zer;
      #pragma unroll
      for (int cf = 0; cf < 6; ++cf){
        s16x8 bb = *(const s16x8*)(bp + cf*16*192 + kc*32);
        acc[0][cf] = mfma16(a0, bb, acc[0][cf]);
        acc[1][cf] = mfma16(a1, bb, acc[1][cf]);
      }
    }
  }
  #pragma unroll
  for (int r = 0; r < 2; ++r)
    #pragma unroll
    for (int cf = 0; cf < 6; ++cf){
      int oc = cf*16 + lr;
      int sprow = sp0 + r*16 + lk*4;
      *reinterpret_cast<f32x4*>(pbuf + ((long)(g*2 + b)*96 + oc)*13824 + sprow) = acc[r][cf];
    }
}

// ---------------- reduce conv2 partials + bias + x -> d_out ----------------
__global__ __launch_bounds__(256) void k_red2(const float* __restrict__ pbuf,
    const float* __restrict__ bias, const float* __restrict__ x, float* __restrict__ out)
{
  int i = blockIdx.x*256 + threadIdx.x;
  if (i >= 2654208) return;
  int oc = (i / 13824) % 96;
  out[i] = pbuf[i] + pbuf[2654208 + i] + pbuf[2*2654208 + i] + bias[oc] + x[i];
}

extern "C" void kernel_launch(void* const* d_in, const int* in_sizes, int n_in,
                              void* d_out, int out_size, void* d_ws, size_t ws_size,
                              hipStream_t stream)
{
  const float* x          = (const float*)d_in[0];
  const float* ln_g       = (const float*)d_in[1];
  const float* ln_b       = (const float*)d_in[2];
  const float* in_proj_w  = (const float*)d_in[3];
  const float* conv_w     = (const float*)d_in[4];
  const float* conv_b     = (const float*)d_in[5];
  const float* xproj_w    = (const float*)d_in[6];
  const float* dt_w       = (const float*)d_in[7];
  const float* dt_b       = (const float*)d_in[8];
  const float* A_log      = (const float*)d_in[9];
  const float* Dp         = (const float*)d_in[10];
  const float* out_proj_w = (const float*)d_in[11];
  const float* f1_w       = (const float*)d_in[12];
  const float* f1_b       = (const float*)d_in[13];
  const float* f2_w       = (const float*)d_in[14];
  const float* f2_b       = (const float*)d_in[15];
  float* out = (float*)d_out;

  const size_t BL = (size_t)BB*LTOT;
  const size_t S  = BL*DINC;

  void* wsp = nullptr;
  (void)hipGetSymbolAddress(&wsp, HIP_SYMBOL(g_ws));
  float* ws = (float*)wsp;
  size_t off = 0;
  auto alloc = [&](size_t n){ float* p = ws + off; off += n; return p; };
  float* xnorm = alloc(BL*C0);
  float* xin   = alloc(S);
  float* gate  = alloc(S);
  float* u     = alloc(3*S);
  float* dtb   = alloc(3*S);
  float* xdbl  = alloc(3*BL*38);
  float* qkv   = alloc(3*S);
  float* Abuf  = alloc(3*DINC*16);
  float* aprod = alloc((size_t)6*DINC*16*NCHUNK);
  float* hend  = alloc((size_t)6*DINC*16*NCHUNK);
  float* attn  = alloc((size_t)BB*DINC*DINC);
  float* outa  = alloc(S);
  float* pbuf  = alloc((size_t)3*2654208);
  // bf16 buffers: sizes below are in FLOATS (2 bf16 per float)
  __hip_bfloat16* inT1 = (__hip_bfloat16*)alloc(2654208);  // 5,308,416 bf16 = [2][13824][192]
  __hip_bfloat16* inT2 = (__hip_bfloat16*)alloc(2654208);  // 5,308,416 bf16
  __hip_bfloat16* Wp1  = (__hip_bfloat16*)alloc(248832);   // 497,664 bf16 = [27][96][192]
  __hip_bfloat16* Wp2  = (__hip_bfloat16*)alloc(248832);

  // 0) pack conv weights to bf16
  k_pack<<<3888, 256, 0, stream>>>(f1_w, f2_w, Wp1, Wp2);
  // 1) layernorm + transpose
  k_ln<<<108, 256, 0, stream>>>(x, ln_g, ln_b, xnorm);
  // 2) in_proj -> xin + silu gate
  k_gemm<<<dim3(432, 6), 256, 0, stream>>>(xnorm, nullptr, nullptr, 96,
      in_proj_w, 0, nullptr, 0, 384, 96, (int)BL, xin, gate, DINC, 0);
  // 3) depthwise causal conv + silu
  k_dwconv<<<62208, 256, 0, stream>>>(xin, conv_w, conv_b, u);
  // 4) xproj
  k_gemm<<<dim3(1296, 1), 256, 0, stream>>>(u, nullptr, nullptr, DINC,
      xproj_w, 38L*192, nullptr, 0, 38, 192, (int)BL, xdbl, nullptr, 38, 1);
  // 5) dt proj + softplus
  k_gemm<<<dim3(1296, 3), 256, 0, stream>>>(xdbl, nullptr, nullptr, 38,
      dt_w, 192L*6, dt_b, 192, 192, 6, (int)BL, dtb, nullptr, DINC, 2);
  // 6) A = -exp(A_log)
  k_prepA<<<36, 256, 0, stream>>>(A_log, Abuf);
  // 7) chunked selective scan (s-states in registers)
  k_scan1<<<6*NCHUNK, 192, 0, stream>>>(u, dtb, xdbl, Abuf, aprod, hend);
  k_scan2<<<72, 256, 0, stream>>>(aprod, hend);
  k_scan3<<<6*NCHUNK, 192, 0, stream>>>(u, dtb, xdbl, Abuf, aprod, Dp, gate, qkv);
  // 8) attention matrix + softmax
  k_zero<<<288, 256, 0, stream>>>(attn, BB*DINC*DINC);
  k_qk<<<432, 256, 0, stream>>>(qkv, qkv + S, attn);
  k_softmax<<<BB*DINC, 64, 0, stream>>>(attn);
  // 9) out_a = v @ attn^T -> f32 (B,L,192)
  k_gemm<<<dim3(432, 3), 256, 0, stream>>>(qkv + 2*S, nullptr, nullptr, DINC,
      attn, (long)DINC*DINC, nullptr, 0, DINC, DINC, LTOT, outa, nullptr, DINC, 1);
  // 10) out_m = (q+k+v) @ out_proj^T -> bf16 into inT2[.][96..192)
  k_gemm<<<dim3(432, 2), 256, 0, stream>>>(qkv, qkv + S, qkv + 2*S, DINC,
      out_proj_w, 0, nullptr, 0, 96, 192, LTOT, (float*)inT2, nullptr, 0, 5);
  // 11) transpose viewed out_a to channel-last bf16
  k_trans<<<dim3(432, 6, 2), 256, 0, stream>>>(outa, inT1);
  // 12) conv3d #1 via MFMA + reduce -> inT2[.][0..96)
  k_convm1<<<648, 256, 0, stream>>>(inT1, Wp1, pbuf);
  k_red1<<<10368, 256, 0, stream>>>(pbuf, f1_b, inT2);
  // 13) conv3d #2 via MFMA + reduce + bias + x -> d_out
  k_convm2<<<648, 256, 0, stream>>>(inT2, Wp2, pbuf);
  k_red2<<<10368, 256, 0, stream>>>(pbuf, f2_b, x, out);
}

// Round 6
// 849.108 us; speedup vs baseline: 4.4213x; 1.1909x over previous
//
#include <hip/hip_runtime.h>
#include <hip/hip_bf16.h>
#include <math.h>

#define BB 2
#define C0 96
#define LTOT 13824
#define DINC 192
#define L4S 3456
#define NCHUNK 216
#define CLEN 64

// Static device workspace (~368 MB .bss)
#define WS_FLOATS 92000000
__device__ __attribute__((aligned(256))) float g_ws[WS_FLOATS];

typedef __bf16 bf16x8 __attribute__((ext_vector_type(8)));
typedef short  s16x8  __attribute__((ext_vector_type(8)));
typedef float  f32x4  __attribute__((ext_vector_type(4)));

__device__ __forceinline__ f32x4 mfma16(s16x8 a, s16x8 b, f32x4 c){
  return __builtin_amdgcn_mfma_f32_16x16x32_bf16(
      __builtin_bit_cast(bf16x8, a), __builtin_bit_cast(bf16x8, b), c, 0, 0, 0);
}

__device__ __forceinline__ int sigma_idx(int dir, int p){
  if (dir == 0) return p;
  if (dir == 1) return LTOT - 1 - p;
  return 4*(p % L4S) + (p / L4S);
}

__device__ __forceinline__ float silu_f(float x){
  return x / (1.f + __expf(-x));
}

// ---------------- LayerNorm: x (B,96,L) -> xnorm (B,L,96) ----------------
__global__ __launch_bounds__(256) void k_ln(const float* __restrict__ x,
    const float* __restrict__ g, const float* __restrict__ bt, float* __restrict__ xn)
{
  int i = blockIdx.x*256 + threadIdx.x;
  if (i >= BB*LTOT) return;
  int b = i / LTOT, ll = i % LTOT;
  const float* xp = x + (size_t)b*C0*LTOT + ll;
  float s = 0.f, ss = 0.f;
  for (int c = 0; c < C0; ++c){ float v = xp[(size_t)c*LTOT]; s += v; ss += v*v; }
  float mu = s * (1.f/C0);
  float var = ss * (1.f/C0) - mu*mu;
  float inv = rsqrtf(var + 1e-5f);
  float* op = xn + (size_t)i*C0;
  for (int c = 0; c < C0; ++c){
    float v = xp[(size_t)c*LTOT];
    op[c] = (v - mu)*inv*g[c] + bt[c];
  }
}

// ---------------- Generic tiled GEMM: O = A(MxK) * W(NxK)^T ----------------
__global__ __launch_bounds__(256) void k_gemm(
    const float* __restrict__ A, const float* __restrict__ A2, const float* __restrict__ A3,
    int lda, const float* __restrict__ W, long wstride, const float* __restrict__ bias,
    int bias_stride, int N, int K, int rpb,
    float* __restrict__ O0, float* __restrict__ O1, int ldo, int mode)
{
  __shared__ float As[32][65];
  __shared__ float Ws[32][65];
  int tid = threadIdx.x;
  long row0 = (long)blockIdx.x * 64;
  int col0 = blockIdx.y * 64;
  int wb = (int)(row0 / rpb);
  const float* Wp = W + (long)wb * wstride;
  float acc[4][4] = {};
  int kk = tid & 31, rb = tid >> 5;
  int nk = (K + 31) >> 5;
  for (int kc = 0; kc < nk; ++kc){
    int k0 = kc*32;
    bool kin = (k0 + kk) < K;
    #pragma unroll
    for (int rr = 0; rr < 8; ++rr){
      int r = rb + rr*8;
      float a = 0.f;
      if (kin){
        long idx = (row0 + r)*(long)lda + k0 + kk;
        a = A[idx];
        if (A2) a += A2[idx] + A3[idx];
      }
      As[kk][r] = a;
      float wv = 0.f;
      if ((col0 + r) < N && kin) wv = Wp[(long)(col0 + r)*K + k0 + kk];
      Ws[kk][r] = wv;
    }
    __syncthreads();
    int r0 = (tid & 15)*4, c0 = (tid >> 4)*4;
    #pragma unroll
    for (int k = 0; k < 32; ++k){
      float av[4], wv[4];
      #pragma unroll
      for (int i = 0; i < 4; ++i){ av[i] = As[k][r0+i]; wv[i] = Ws[k][c0+i]; }
      #pragma unroll
      for (int i = 0; i < 4; ++i)
        #pragma unroll
        for (int j = 0; j < 4; ++j) acc[i][j] += av[i]*wv[j];
    }
    __syncthreads();
  }
  int r0 = (tid & 15)*4, c0 = (tid >> 4)*4;
  #pragma unroll
  for (int i = 0; i < 4; ++i){
    long row = row0 + r0 + i;
    #pragma unroll
    for (int j = 0; j < 4; ++j){
      int col = col0 + c0 + j;
      if (col >= N) continue;
      float v = acc[i][j];
      if (mode == 0){
        if (col < DINC) O0[row*DINC + col] = v;
        else            O1[row*DINC + col - DINC] = silu_f(v);
      } else if (mode == 1){
        O0[row*(long)ldo + col] = v;
      } else if (mode == 2){
        float xv = v + bias[wb*bias_stride + col];
        O0[row*(long)ldo + col] = (xv > 20.f) ? xv : log1pf(__expf(xv));
      } else if (mode == 5){
        ((__hip_bfloat16*)O0)[row*192 + 96 + col] = __float2bfloat16(v);
      }
    }
  }
}

// ---------------- depthwise causal conv1d (permuted) + SiLU ----------------
__global__ __launch_bounds__(256) void k_dwconv(const float* __restrict__ xin,
    const float* __restrict__ cw, const float* __restrict__ cb, float* __restrict__ u)
{
  long i = (long)blockIdx.x*256 + threadIdx.x;
  if (i >= 3L*BB*LTOT*DINC) return;
  int d = (int)(i % DINC); long t = i / DINC;
  int p = (int)(t % LTOT); t /= LTOT;
  int b = (int)(t % BB); int dir = (int)(t / BB);
  float acc = cb[dir*DINC + d];
  const float* wp = cw + ((long)dir*DINC + d)*4;
  #pragma unroll
  for (int kk = 0; kk < 4; ++kk){
    int pp = p - 3 + kk;
    if (pp >= 0){
      int l = sigma_idx(dir, pp);
      acc += xin[((long)b*LTOT + l)*DINC + d] * wp[kk];
    }
  }
  u[i] = silu_f(acc);
}

__global__ __launch_bounds__(256) void k_prepA(const float* __restrict__ al, float* __restrict__ A){
  int i = blockIdx.x*256 + threadIdx.x;
  if (i < 3*DINC*16) A[i] = -__expf(al[i]);
}

// ---------------- scan phase 1: per-chunk local scan, 16 s-states in regs ----------------
__global__ __launch_bounds__(192) void k_scan1(const float* __restrict__ u,
    const float* __restrict__ dt, const float* __restrict__ xdbl,
    const float* __restrict__ Abuf, float* __restrict__ aprod, float* __restrict__ hend)
{
  __shared__ float sB[CLEN][16];
  int d = threadIdx.x;
  int c  = blockIdx.x % NCHUNK;
  int bd = blockIdx.x / NCHUNK;
  int dir = bd >> 1;
  long pbase = (long)bd*LTOT + (long)c*CLEN;
  for (int idx = d; idx < CLEN*16; idx += 192){
    int j = idx >> 4, s = idx & 15;
    sB[j][s] = xdbl[(pbase + j)*38 + 6 + s];
  }
  __syncthreads();
  float A[16], h[16];
  #pragma unroll
  for (int s = 0; s < 16; ++s){
    A[s] = Abuf[((long)dir*DINC + d)*16 + s];
    h[s] = 0.f;
  }
  float sum_dt = 0.f;
  for (int j = 0; j < CLEN; ++j){
    long p = pbase + j;
    float ldt = dt[p*DINC + d];
    float lu  = u [p*DINC + d];
    sum_dt += ldt;
    float du = ldt*lu;
    #pragma unroll
    for (int s = 0; s < 16; ++s){
      float dA = __expf(ldt * A[s]);
      h[s] = dA*h[s] + du*sB[j][s];
    }
  }
  long oi = (((long)bd*DINC + d)*NCHUNK + c)*16;
  #pragma unroll
  for (int s = 0; s < 16; ++s){
    aprod[oi + s] = __expf(A[s]*sum_dt);
    hend [oi + s] = h[s];
  }
}

// ---------------- scan phase 2: scan over chunks; aprod becomes h_in ----------------
__global__ __launch_bounds__(256) void k_scan2(float* __restrict__ aprod, const float* __restrict__ hend){
  long i = (long)blockIdx.x*256 + threadIdx.x;
  if (i >= 6L*DINC*16) return;
  int s = (int)(i & 15); long t = i >> 4;
  int d = (int)(t % DINC); int bd = (int)(t / DINC);
  long base = (((long)bd*DINC + d)*NCHUNK)*16 + s;
  float H = 0.f;
  for (int c = 0; c < NCHUNK; ++c){
    long idx = base + (long)c*16;
    float a = aprod[idx], he = hend[idx];
    aprod[idx] = H;
    H = he + a*H;
  }
}

// ---------------- scan phase 3: recompute with h_in, y-dot in regs, gate+inv-perm ----------------
__global__ __launch_bounds__(192) void k_scan3(const float* __restrict__ u,
    const float* __restrict__ dt, const float* __restrict__ xdbl,
    const float* __restrict__ Abuf, const float* __restrict__ hin,
    const float* __restrict__ Dp, const float* __restrict__ gate, float* __restrict__ qkv)
{
  __shared__ float sB[CLEN][16];
  __shared__ float sC[CLEN][16];
  int d = threadIdx.x;
  int c  = blockIdx.x % NCHUNK;
  int bd = blockIdx.x / NCHUNK;
  int dir = bd >> 1, b = bd & 1;
  long pbase = (long)bd*LTOT + (long)c*CLEN;
  for (int idx = d; idx < CLEN*16; idx += 192){
    int j = idx >> 4, s = idx & 15;
    sB[j][s] = xdbl[(pbase + j)*38 + 6  + s];
    sC[j][s] = xdbl[(pbase + j)*38 + 22 + s];
  }
  __syncthreads();
  float A[16], h[16];
  long oi = (((long)bd*DINC + d)*NCHUNK + c)*16;
  #pragma unroll
  for (int s = 0; s < 16; ++s){
    A[s] = Abuf[((long)dir*DINC + d)*16 + s];
    h[s] = hin[oi + s];
  }
  float Dv = Dp[dir*DINC + d];
  for (int j = 0; j < CLEN; ++j){
    long p = pbase + j;
    float ldt = dt[p*DINC + d];
    float lu  = u [p*DINC + d];
    float du = ldt*lu;
    float y = 0.f;
    #pragma unroll
    for (int s = 0; s < 16; ++s){
      float dA = __expf(ldt * A[s]);
      h[s] = dA*h[s] + du*sB[j][s];
      y += h[s]*sC[j][s];
    }
    int pl = c*CLEN + j;
    int l = sigma_idx(dir, pl);
    long li = (long)b*LTOT + l;
    qkv[(((long)dir*BB + b)*LTOT + l)*DINC + d] = (y + lu*Dv) * gate[li*DINC + d];
  }
}

__global__ __launch_bounds__(256) void k_zero(float* __restrict__ p, int n){
  int i = blockIdx.x*256 + threadIdx.x;
  if (i < n) p[i] = 0.f;
}

// ---------------- attn_raw[b,d,e] += sum_l q[b,l,d] k[b,l,e] ----------------
__global__ __launch_bounds__(256) void k_qk(const float* __restrict__ q,
    const float* __restrict__ k, float* __restrict__ attn)
{
  __shared__ float Qs[32][64];
  __shared__ float Ks[32][64];
  int tid = threadIdx.x;
  int bx = blockIdx.x;
  int lc = bx % 24; int et = (bx/24) % 3; int dtl = (bx/72) % 3; int b = bx/216;
  long base = (long)b*LTOT;
  int l0 = lc*576;
  float acc[4][4] = {};
  int col = tid & 63, rbase = tid >> 6;
  for (int ls = 0; ls < 576; ls += 32){
    #pragma unroll
    for (int rr = 0; rr < 8; ++rr){
      int r = rbase + rr*4;
      long l = base + l0 + ls + r;
      Qs[r][col] = q[l*DINC + dtl*64 + col];
      Ks[r][col] = k[l*DINC + et *64 + col];
    }
    __syncthreads();
    int d0 = (tid & 15)*4, e0 = (tid >> 4)*4;
    #pragma unroll
    for (int ll = 0; ll < 32; ++ll){
      float qa[4], ka[4];
      #pragma unroll
      for (int i = 0; i < 4; ++i){ qa[i] = Qs[ll][d0+i]; ka[i] = Ks[ll][e0+i]; }
      #pragma unroll
      for (int i = 0; i < 4; ++i)
        #pragma unroll
        for (int j = 0; j < 4; ++j) acc[i][j] += qa[i]*ka[j];
    }
    __syncthreads();
  }
  int d0 = (tid & 15)*4, e0 = (tid >> 4)*4;
  #pragma unroll
  for (int i = 0; i < 4; ++i)
    #pragma unroll
    for (int j = 0; j < 4; ++j)
      atomicAdd(&attn[((long)b*DINC + dtl*64 + d0 + i)*DINC + et*64 + e0 + j], acc[i][j]);
}

__global__ __launch_bounds__(64) void k_softmax(float* __restrict__ attn){
  int row = blockIdx.x, tid = threadIdx.x;
  float* p = attn + (long)row*DINC;
  float v0 = p[tid], v1 = p[tid+64], v2 = p[tid+128];
  float m = fmaxf(v0, fmaxf(v1, v2));
  #pragma unroll
  for (int off = 32; off >= 1; off >>= 1) m = fmaxf(m, __shfl_xor(m, off));
  float e0 = __expf(v0-m), e1 = __expf(v1-m), e2 = __expf(v2-m);
  float s = e0 + e1 + e2;
  #pragma unroll
  for (int off = 32; off >= 1; off >>= 1) s += __shfl_xor(s, off);
  float inv = 1.f/s;
  p[tid] = e0*inv; p[tid+64] = e1*inv; p[tid+128] = e2*inv;
}

// ---------------- pack conv weights (96,192,27) f32 -> bf16 [tap][kc][oc][icl] ----------------
__global__ __launch_bounds__(256) void k_pack(const float* __restrict__ w1,
    const float* __restrict__ w2, __hip_bfloat16* __restrict__ p1, __hip_bfloat16* __restrict__ p2)
{
  int i = blockIdx.x*256 + threadIdx.x;
  if (i >= 2*497664) return;
  int which = i / 497664; int r = i % 497664;
  int icl = r & 31; int oc = (r >> 5) % 96; int kc = (r / 3072) % 6; int t = r / 18432;
  const float* w = which ? w2 : w1;
  float v = w[(long)oc*5184 + (kc*32 + icl)*27 + t];
  (which ? p2 : p1)[r] = __float2bfloat16(v);
}

// ---------------- transpose viewed (B,192,13824) f32 -> bf16 [b][sp][192] ----------------
__global__ __launch_bounds__(256) void k_trans(const float* __restrict__ src,
    __hip_bfloat16* __restrict__ dst)
{
  __shared__ float lds[32][33];
  int tx = threadIdx.x & 31, ty = threadIdx.x >> 5;
  int sb = blockIdx.x*32;
  int cb = blockIdx.y*32;
  int b  = blockIdx.z;
  const float* s = src + (long)b*2654208;
  #pragma unroll
  for (int j = 0; j < 4; ++j)
    lds[ty + j*8][tx] = s[(long)(cb + ty + j*8)*13824 + sb + tx];
  __syncthreads();
  #pragma unroll
  for (int j = 0; j < 4; ++j)
    dst[((long)b*13824 + sb + ty + j*8)*192 + cb + tx] = __float2bfloat16(lds[tx][ty + j*8]);
}

// ---------------- conv3d via LDS-staged double-buffered implicit GEMM ----------------
// grid 648 = 3 kd-groups x 2 batch x 108 sp-tiles(128); block 128 thr (2 waves)
// CONV=1: D rows=oc -> pbuf[(g,b)][sp][96]; CONV=2: D rows=sp -> pbuf[(g,b)][96][sp]
template<int CONV>
__global__ __launch_bounds__(128, 2) void k_convm(const __hip_bfloat16* __restrict__ inT,
    const __hip_bfloat16* __restrict__ Wp, float* __restrict__ pbuf)
{
  __shared__ short As[2][128][32];
  __shared__ short Ws[2][96][32];
  int tid = threadIdx.x;
  int bx = blockIdx.x;
  int g = bx / 216; int rem = bx % 216; int b = rem / 108; int tile = rem % 108;
  int sp0 = tile * 128;
  int kd = g - 1;
  int lane = tid & 63, wid = tid >> 6;
  int lr = lane & 15, lk = lane >> 4;
  const s16x8 zer = {0,0,0,0,0,0,0,0};

  // per-thread A-staging rows (4 rows: (tid>>2)+32k), chunk = tid&3
  int chnk = tid & 3;
  int hh[4], wwv[4], zzv[4], spv[4];
  #pragma unroll
  for (int k = 0; k < 4; ++k){
    int sp = sp0 + (tid >> 2) + 32*k;
    spv[k] = sp; hh[k] = sp/576; wwv[k] = (sp/24)%24; zzv[k] = sp%24;
  }

  f32x4 acc[6][4];
  #pragma unroll
  for (int i = 0; i < 6; ++i)
    #pragma unroll
    for (int j = 0; j < 4; ++j) acc[i][j] = f32x4{0.f,0.f,0.f,0.f};

  s16x8 av[4], wv[3];
  // prologue: load step 0
  {
    int t = 0, kc = 0;
    int dw = -1, dz = -1;
    #pragma unroll
    for (int k = 0; k < 4; ++k){
      av[k] = zer;
      bool ok = ((unsigned)(hh[k]+kd) < 24u) && ((unsigned)(wwv[k]+dw) < 24u) && ((unsigned)(zzv[k]+dz) < 24u);
      if (ok){
        int spp = spv[k] + kd*576 + dw*24 + dz;
        av[k] = *(const s16x8*)(inT + ((long)(b*13824 + spp))*192 + kc*32 + chnk*8);
      }
    }
    long wb = ((long)(g*9 + t)*6 + kc)*3072;
    #pragma unroll
    for (int k = 0; k < 3; ++k)
      wv[k] = *(const s16x8*)(Wp + wb + (long)(tid + 128*k)*8);
  }
  #pragma unroll
  for (int k = 0; k < 4; ++k)
    *(s16x8*)&As[0][(tid>>2) + 32*k][chnk*8] = av[k];
  #pragma unroll
  for (int k = 0; k < 3; ++k)
    *(s16x8*)&Ws[0][(tid + 128*k) >> 2][chnk*8] = wv[k];
  __syncthreads();

  for (int s = 0; s < 54; ++s){
    int buf = s & 1;
    // issue next step's global loads (T14: issue-early)
    int sn = s + 1;
    if (sn < 54){
      int t = sn / 6, kc = sn - 6*t;
      int td3 = t / 3;
      int dw = td3 - 1, dz = t - 3*td3 - 1;
      #pragma unroll
      for (int k = 0; k < 4; ++k){
        av[k] = zer;
        bool ok = ((unsigned)(hh[k]+kd) < 24u) && ((unsigned)(wwv[k]+dw) < 24u) && ((unsigned)(zzv[k]+dz) < 24u);
        if (ok){
          int spp = spv[k] + kd*576 + dw*24 + dz;
          av[k] = *(const s16x8*)(inT + ((long)(b*13824 + spp))*192 + kc*32 + chnk*8);
        }
      }
      long wb = ((long)(g*9 + t)*6 + kc)*3072;
      #pragma unroll
      for (int k = 0; k < 3; ++k)
        wv[k] = *(const s16x8*)(Wp + wb + (long)(tid + 128*k)*8);
    }
    // compute current buffer
    s16x8 bfr[4];
    #pragma unroll
    for (int c = 0; c < 4; ++c)
      bfr[c] = *(const s16x8*)&As[buf][wid*64 + c*16 + lr][lk*8];
    #pragma unroll
    for (int cf = 0; cf < 6; ++cf){
      s16x8 wf = *(const s16x8*)&Ws[buf][cf*16 + lr][lk*8];
      #pragma unroll
      for (int c = 0; c < 4; ++c){
        if (CONV == 1) acc[cf][c] = mfma16(wf, bfr[c], acc[cf][c]);
        else           acc[cf][c] = mfma16(bfr[c], wf, acc[cf][c]);
      }
    }
    // write next buffer (vmcnt inserted by compiler), then barrier
    if (sn < 54){
      #pragma unroll
      for (int k = 0; k < 4; ++k)
        *(s16x8*)&As[buf^1][(tid>>2) + 32*k][chnk*8] = av[k];
      #pragma unroll
      for (int k = 0; k < 3; ++k)
        *(s16x8*)&Ws[buf^1][(tid + 128*k) >> 2][chnk*8] = wv[k];
    }
    __syncthreads();
  }

  long gb = (long)(g*2 + b);
  #pragma unroll
  for (int cf = 0; cf < 6; ++cf)
    #pragma unroll
    for (int c = 0; c < 4; ++c){
      if (CONV == 1){
        int sp = sp0 + wid*64 + c*16 + lr;
        int oc0 = cf*16 + lk*4;
        *reinterpret_cast<f32x4*>(pbuf + (gb*13824 + sp)*96 + oc0) = acc[cf][c];
      } else {
        int oc = cf*16 + lr;
        int spr = sp0 + wid*64 + c*16 + lk*4;
        *reinterpret_cast<f32x4*>(pbuf + (gb*96 + oc)*13824 + spr) = acc[cf][c];
      }
    }
}

// ---------------- reduce conv1 partials + bias -> bf16 inT2[.][0..96) ----------------
__global__ __launch_bounds__(256) void k_red1(const float* __restrict__ pbuf,
    const float* __restrict__ bias, __hip_bfloat16* __restrict__ inT2)
{
  int i = blockIdx.x*256 + threadIdx.x;
  if (i >= 2654208) return;
  int oc = i % 96;
  float v = pbuf[i] + pbuf[2654208 + i] + pbuf[2*2654208 + i] + bias[oc];
  long row = i / 96;
  inT2[row*192 + oc] = __float2bfloat16(v);
}

// ---------------- reduce conv2 partials + bias + x -> d_out ----------------
__global__ __launch_bounds__(256) void k_red2(const float* __restrict__ pbuf,
    const float* __restrict__ bias, const float* __restrict__ x, float* __restrict__ out)
{
  int i = blockIdx.x*256 + threadIdx.x;
  if (i >= 2654208) return;
  int oc = (i / 13824) % 96;
  out[i] = pbuf[i] + pbuf[2654208 + i] + pbuf[2*2654208 + i] + bias[oc] + x[i];
}

extern "C" void kernel_launch(void* const* d_in, const int* in_sizes, int n_in,
                              void* d_out, int out_size, void* d_ws, size_t ws_size,
                              hipStream_t stream)
{
  const float* x          = (const float*)d_in[0];
  const float* ln_g       = (const float*)d_in[1];
  const float* ln_b       = (const float*)d_in[2];
  const float* in_proj_w  = (const float*)d_in[3];
  const float* conv_w     = (const float*)d_in[4];
  const float* conv_b     = (const float*)d_in[5];
  const float* xproj_w    = (const float*)d_in[6];
  const float* dt_w       = (const float*)d_in[7];
  const float* dt_b       = (const float*)d_in[8];
  const float* A_log      = (const float*)d_in[9];
  const float* Dp         = (const float*)d_in[10];
  const float* out_proj_w = (const float*)d_in[11];
  const float* f1_w       = (const float*)d_in[12];
  const float* f1_b       = (const float*)d_in[13];
  const float* f2_w       = (const float*)d_in[14];
  const float* f2_b       = (const float*)d_in[15];
  float* out = (float*)d_out;

  const size_t BL = (size_t)BB*LTOT;
  const size_t S  = BL*DINC;

  void* wsp = nullptr;
  (void)hipGetSymbolAddress(&wsp, HIP_SYMBOL(g_ws));
  float* ws = (float*)wsp;
  size_t off = 0;
  auto alloc = [&](size_t n){ float* p = ws + off; off += n; return p; };
  float* xnorm = alloc(BL*C0);
  float* xin   = alloc(S);
  float* gate  = alloc(S);
  float* u     = alloc(3*S);
  float* dtb   = alloc(3*S);
  float* xdbl  = alloc(3*BL*38);
  float* qkv   = alloc(3*S);
  float* Abuf  = alloc(3*DINC*16);
  float* aprod = alloc((size_t)6*DINC*16*NCHUNK);
  float* hend  = alloc((size_t)6*DINC*16*NCHUNK);
  float* attn  = alloc((size_t)BB*DINC*DINC);
  float* outa  = alloc(S);
  float* pbuf  = alloc((size_t)3*2654208);
  // bf16 buffers: sizes in FLOATS (2 bf16 per float)
  __hip_bfloat16* inT1 = (__hip_bfloat16*)alloc(2654208);  // [2][13824][192] bf16
  __hip_bfloat16* inT2 = (__hip_bfloat16*)alloc(2654208);
  __hip_bfloat16* Wp1  = (__hip_bfloat16*)alloc(248832);   // [27][6][96][32] bf16
  __hip_bfloat16* Wp2  = (__hip_bfloat16*)alloc(248832);

  // 0) pack conv weights to bf16
  k_pack<<<3888, 256, 0, stream>>>(f1_w, f2_w, Wp1, Wp2);
  // 1) layernorm + transpose
  k_ln<<<108, 256, 0, stream>>>(x, ln_g, ln_b, xnorm);
  // 2) in_proj -> xin + silu gate
  k_gemm<<<dim3(432, 6), 256, 0, stream>>>(xnorm, nullptr, nullptr, 96,
      in_proj_w, 0, nullptr, 0, 384, 96, (int)BL, xin, gate, DINC, 0);
  // 3) depthwise causal conv + silu
  k_dwconv<<<62208, 256, 0, stream>>>(xin, conv_w, conv_b, u);
  // 4) xproj
  k_gemm<<<dim3(1296, 1), 256, 0, stream>>>(u, nullptr, nullptr, DINC,
      xproj_w, 38L*192, nullptr, 0, 38, 192, (int)BL, xdbl, nullptr, 38, 1);
  // 5) dt proj + softplus
  k_gemm<<<dim3(1296, 3), 256, 0, stream>>>(xdbl, nullptr, nullptr, 38,
      dt_w, 192L*6, dt_b, 192, 192, 6, (int)BL, dtb, nullptr, DINC, 2);
  // 6) A = -exp(A_log)
  k_prepA<<<36, 256, 0, stream>>>(A_log, Abuf);
  // 7) chunked selective scan (s-states in registers)
  k_scan1<<<6*NCHUNK, 192, 0, stream>>>(u, dtb, xdbl, Abuf, aprod, hend);
  k_scan2<<<72, 256, 0, stream>>>(aprod, hend);
  k_scan3<<<6*NCHUNK, 192, 0, stream>>>(u, dtb, xdbl, Abuf, aprod, Dp, gate, qkv);
  // 8) attention matrix + softmax
  k_zero<<<288, 256, 0, stream>>>(attn, BB*DINC*DINC);
  k_qk<<<432, 256, 0, stream>>>(qkv, qkv + S, attn);
  k_softmax<<<BB*DINC, 64, 0, stream>>>(attn);
  // 9) out_a = v @ attn^T -> f32 (B,L,192)
  k_gemm<<<dim3(432, 3), 256, 0, stream>>>(qkv + 2*S, nullptr, nullptr, DINC,
      attn, (long)DINC*DINC, nullptr, 0, DINC, DINC, LTOT, outa, nullptr, DINC, 1);
  // 10) out_m = (q+k+v) @ out_proj^T -> bf16 into inT2[.][96..192)
  k_gemm<<<dim3(432, 2), 256, 0, stream>>>(qkv, qkv + S, qkv + 2*S, DINC,
      out_proj_w, 0, nullptr, 0, 96, 192, LTOT, (float*)inT2, nullptr, 0, 5);
  // 11) transpose viewed out_a to channel-last bf16
  k_trans<<<dim3(432, 6, 2), 256, 0, stream>>>(outa, inT1);
  // 12) conv3d #1 (LDS dbuf MFMA) + reduce -> inT2[.][0..96)
  k_convm<1><<<648, 128, 0, stream>>>(inT1, Wp1, pbuf);
  k_red1<<<10368, 256, 0, stream>>>(pbuf, f1_b, inT2);
  // 13) conv3d #2 (LDS dbuf MFMA) + reduce + bias + x -> d_out
  k_convm<2><<<648, 128, 0, stream>>>(inT2, Wp2, pbuf);
  k_red2<<<10368, 256, 0, stream>>>(pbuf, f2_b, x, out);
}